// Round 17
// baseline (543.225 us; speedup 1.0000x reference)
//
#include <hip/hip_runtime.h>
#include <math.h>

#define N_NODES_C 100000
#define N_EDGES_C 3200000
// D_NODE=16, D_EDGE=8, D_HIDDEN=16

#define NORM_MSG_TP 0.08838834764831845f   // 1/sqrt(16*8)
#define NORM_UPD_TP 0.0625f                // 1/sqrt(16*16)
#define NORM_LIN    0.25f                  // 1/sqrt(16)

#define NBUK  782      // buckets of 128 nodes (99999>>7 = 781)
#define NBUKP 784      // padded row (entries 782/783 hold total after scan)
#define BPB   8000     // edges per bucketize block: 3.2M/8000 = 400 exact
#define NBLK_BUK 400

typedef float f32x4 __attribute__((ext_vector_type(4)));
typedef short bf16x8 __attribute__((ext_vector_type(8)));
typedef int   int4v  __attribute__((ext_vector_type(4)));

__device__ __forceinline__ float silu_f(float v) {
  return v / (1.0f + __expf(-v));
}

__device__ __forceinline__ void atomic_add_hw(float* p, float v) {
  unsafeAtomicAdd(p, v);
}

// float -> bf16 bits (round to nearest even)
__device__ __forceinline__ unsigned int bf16_bits(float f) {
  unsigned int b = __float_as_uint(f);
  return (b + 0x7fffu + ((b >> 16) & 1u)) >> 16;
}
__device__ __forceinline__ unsigned int pack_bf16x2(float lo, float hi) {
  return bf16_bits(lo) | (bf16_bits(hi) << 16);
}
__device__ __forceinline__ float unlo(unsigned int w) { return __uint_as_float(w << 16); }
__device__ __forceinline__ float unhi(unsigned int w) { return __uint_as_float(w & 0xffff0000u); }

// ---------------- bucketize: LDS counting-sort by 128-node bucket ----------------

__global__ __launch_bounds__(256) void bucketize_kernel(
    const int* __restrict__ row,      // eidx[0..E): dest nodes
    int* __restrict__ bids,           // [E] packed (eid<<7)|local, bucket-grouped per block
    int* __restrict__ sct)            // [NBLK_BUK][NBUKP] per-block exclusive starts
{
  __shared__ int lhist[NBUKP];
  __shared__ int lcur[NBUKP];
  __shared__ int partial[256];
  __shared__ int lids[BPB];
  const int t = threadIdx.x;
  const int base = blockIdx.x * BPB;

  for (int i = t; i < NBUKP; i += 256) lhist[i] = 0;
  __syncthreads();
  for (int k = t; k < BPB; k += 256)
    atomicAdd(&lhist[row[base + k] >> 7], 1);
  __syncthreads();

  // exclusive scan over lhist[0..783]
  int csum = 0;
  if (t < 196) {
    int s = 0;
#pragma unroll
    for (int j = 0; j < 4; ++j) {
      const int v = lhist[t * 4 + j];
      lhist[t * 4 + j] = s;
      s += v;
    }
    csum = s;
  }
  partial[t] = csum;
  __syncthreads();
  for (int o = 1; o < 256; o <<= 1) {
    int tv = (t >= o) ? partial[t - o] : 0;
    __syncthreads();
    partial[t] += tv;
    __syncthreads();
  }
  const int add = partial[t] - csum;
  if (t < 196) {
#pragma unroll
    for (int j = 0; j < 4; ++j) lhist[t * 4 + j] += add;
  }
  __syncthreads();
  for (int i = t; i < NBUKP; i += 256) lcur[i] = lhist[i];
  __syncthreads();

  for (int k = t; k < BPB; k += 256) {
    const int r = row[base + k];
    const int b = r >> 7;
    const int p = atomicAdd(&lcur[b], 1);
    lids[p] = ((base + k) << 7) | (r & 127);
  }
  __syncthreads();

  for (int i = t; i < NBUKP; i += 256)
    sct[blockIdx.x * NBUKP + i] = lhist[i];
  for (int k = t; k < BPB; k += 256)
    bids[base + k] = lids[k];
}

// ---------------- colscan: per-bucket scan over the 400 block counts ----------------
// block b: colpre[blk][b] = sum_{blk'<blk} count[blk'][b]; btot[b] = total.

__global__ __launch_bounds__(256) void colscan_kernel(
    const int* __restrict__ sct, int* __restrict__ colpre, int* __restrict__ btot) {
  __shared__ int sa[512], sb[512];
  const int t = threadIdx.x;
  const int b = blockIdx.x;           // bucket 0..781
  const int c0 = (t < NBLK_BUK)
      ? sct[t * NBUKP + b + 1] - sct[t * NBUKP + b] : 0;
  const int c1 = (t + 256 < NBLK_BUK)
      ? sct[(t + 256) * NBUKP + b + 1] - sct[(t + 256) * NBUKP + b] : 0;
  sa[t] = c0; sa[t + 256] = c1;
  int* src = sa; int* dst = sb;
  for (int o = 1; o < 512; o <<= 1) {
    __syncthreads();
    dst[t]       = src[t]       + ((t >= o) ? src[t - o] : 0);
    dst[t + 256] = src[t + 256] + ((t + 256 >= o) ? src[t + 256 - o] : 0);
    int* tmp = src; src = dst; dst = tmp;
  }
  __syncthreads();
  if (t < NBLK_BUK) colpre[t * NBUKP + b] = src[t] - c0;                 // exclusive
  if (t + 256 < NBLK_BUK) colpre[(t + 256) * NBUKP + b] = src[t + 256] - c1;
  if (t == 0) btot[b] = src[NBLK_BUK - 1];
}

// ---------------- generic scans (used for bucket bases over btot[782]) ----------------

__global__ __launch_bounds__(256) void scan_block(
    const int* __restrict__ cnt, int* __restrict__ off, int* __restrict__ bsum, int n) {
  __shared__ int s[256];
  const int t = threadIdx.x;
  const int i = blockIdx.x * 256 + t;
  const int v = (i < n) ? cnt[i] : 0;
  s[t] = v;
  __syncthreads();
#pragma unroll
  for (int o = 1; o < 256; o <<= 1) {
    int tv = (t >= o) ? s[t - o] : 0;
    __syncthreads();
    s[t] += tv;
    __syncthreads();
  }
  if (i < n) off[i] = s[t] - v;
  if (t == 255) bsum[blockIdx.x] = s[255];
}

__global__ void scan_bsum(int* __restrict__ bsum, int nb) {
  __shared__ int s[512];
  const int t = threadIdx.x;
  const int v = (t < nb) ? bsum[t] : 0;
  s[t] = v;
  __syncthreads();
#pragma unroll
  for (int o = 1; o < 512; o <<= 1) {
    int tv = (t >= o) ? s[t - o] : 0;
    __syncthreads();
    s[t] += tv;
    __syncthreads();
  }
  if (t < nb) bsum[t] = s[t] - v;
}

__global__ __launch_bounds__(256) void scan_add(
    int* __restrict__ off, const int* __restrict__ bsum, int n, int total) {
  int i = blockIdx.x * 256 + threadIdx.x;
  if (i < n) off[i] += bsum[blockIdx.x];
  if (i == 0) off[n] = total;
}

// ---------------- bscatter: place codes at bucket-contiguous global slots ----------------
// slot = boff[b] + colpre[blk][b] + (k - sct[blk][b]); b found by binary search
// over the LDS-staged sct row. Writes are runs (~10 consecutive) per (blk,b).

__global__ __launch_bounds__(256) void bscatter_kernel(
    const int* __restrict__ bids, const int* __restrict__ sct,
    const int* __restrict__ colpre, const int* __restrict__ boff,
    int* __restrict__ bsort) {
  __shared__ int srow[NBUKP];
  __shared__ int crow[NBUKP];
  const int t = threadIdx.x;
  const int blk = blockIdx.x;
  for (int i = t; i < NBUKP; i += 256) {
    srow[i] = sct[blk * NBUKP + i];
    crow[i] = colpre[blk * NBUKP + i];
  }
  __syncthreads();
  for (int k = t; k < BPB; k += 256) {
    const int code = bids[blk * BPB + k];
    int lo = 0, hi = 783;            // srow[0]=0<=k, srow[783]=BPB>k
    while (hi - lo > 1) {
      const int mid = (lo + hi) >> 1;
      if (srow[mid] <= k) lo = mid; else hi = mid;
    }
    const int slot = boff[lo] + crow[lo] + (k - srow[lo]);
    bsort[slot] = code;
  }
}

// ---------------- x -> bf16 table (3.2 MB, L2-resident) ----------------

__global__ __launch_bounds__(256) void xcast_kernel(
    const float* __restrict__ x, unsigned short* __restrict__ xb) {
  const int i = blockIdx.x * 256 + threadIdx.x;
  if (i < N_NODES_C * 2) {
    const float4 a = *reinterpret_cast<const float4*>(x + (size_t)i * 8);
    const float4 b = *reinterpret_cast<const float4*>(x + (size_t)i * 8 + 4);
    uint4 w;
    w.x = pack_bf16x2(a.x, a.y); w.y = pack_bf16x2(a.z, a.w);
    w.z = pack_bf16x2(b.x, b.y); w.w = pack_bf16x2(b.z, b.w);
    *reinterpret_cast<uint4*>(xb + (size_t)i * 8) = w;
  }
}

// ---------------- msg6: swapped-operand MFMA messages, EDGE order, linear nt store ----------------

#define COLS_TILE(T, CC) do {                                        \
    CC = __builtin_nontemporal_load(&eidx[N_EDGES_C + (T) * 16 + el]); \
  } while (0)

#define GATH_TILE(T, CC, XH, FA, FB) do {                            \
    const int e_ = (T) * 16 + el;                                    \
    XH = *reinterpret_cast<const uint4*>(xb + (size_t)(CC) * 16 + 8 * ghalf); \
    FA = __builtin_nontemporal_load(                                 \
        reinterpret_cast<const f32x4*>(ea + (size_t)e_ * 8));        \
    FB = __builtin_nontemporal_load(                                 \
        reinterpret_cast<const f32x4*>(ea + (size_t)e_ * 8 + 4));    \
  } while (0)

__global__ __launch_bounds__(256) void msg6_kernel(
    const int*   __restrict__ eidx,   // [2,E]
    const float* __restrict__ ea,     // [E,8] fp32
    const float* __restrict__ Wtp,    // [16,8,16]
    const unsigned short* __restrict__ xb,  // [N,16] bf16
    unsigned int* __restrict__ msgb)  // [E*8] words, edge order
{
  const int lane  = threadIdx.x & 63;
  const int el    = lane & 15;
  const int g     = lane >> 4;
  const int gsel  = g >> 1;
  const int ghalf = g & 1;

  // A frag (constant W): aq[q][t] = Wtp[i=8*ghalf+t][j=2q+gsel][h=el] (k = j*16+i)
  bf16x8 aq[4];
#pragma unroll
  for (int q = 0; q < 4; ++q) {
#pragma unroll
    for (int t = 0; t < 8; ++t) {
      const float w = Wtp[(8 * ghalf + t) * 128 + (2 * q + gsel) * 16 + el];
      aq[q][t] = (short)bf16_bits(w);
    }
  }

  const int s = gridDim.x * 4;
  const int wid = blockIdx.x * 4 + (threadIdx.x >> 6);
  const int ntiles = N_EDGES_C / 16;  // 200000

  int cc_a = 0, cc_b = 0;
  uint4 xh_a; xh_a.x = xh_a.y = xh_a.z = xh_a.w = 0;
  f32x4 fa_a = {0.f, 0.f, 0.f, 0.f}, fb_a = {0.f, 0.f, 0.f, 0.f};

  if (wid < ntiles)     COLS_TILE(wid, cc_a);
  if (wid + s < ntiles) COLS_TILE(wid + s, cc_b);
  if (wid < ntiles)     GATH_TILE(wid, cc_a, xh_a, fa_a, fb_a);

  for (int t = wid; t < ntiles; t += s) {
    int cc_c = 0;
    if (t + 2 * s < ntiles) COLS_TILE(t + 2 * s, cc_c);
    uint4 xh_b; xh_b.x = xh_b.y = xh_b.z = xh_b.w = 0;
    f32x4 fa_b = {0.f, 0.f, 0.f, 0.f}, fb_b = {0.f, 0.f, 0.f, 0.f};
    if (t + s < ntiles) GATH_TILE(t + s, cc_b, xh_b, fa_b, fb_b);

    float xf[8];
    xf[0] = unlo(xh_a.x); xf[1] = unhi(xh_a.x);
    xf[2] = unlo(xh_a.y); xf[3] = unhi(xh_a.y);
    xf[4] = unlo(xh_a.z); xf[5] = unhi(xh_a.z);
    xf[6] = unlo(xh_a.w); xf[7] = unhi(xh_a.w);
    float eq[4];
    eq[0] = gsel ? fa_a[1] : fa_a[0];
    eq[1] = gsel ? fa_a[3] : fa_a[2];
    eq[2] = gsel ? fb_a[1] : fb_a[0];
    eq[3] = gsel ? fb_a[3] : fb_a[2];

    f32x4 acc = {0.f, 0.f, 0.f, 0.f};
#pragma unroll
    for (int q = 0; q < 4; ++q) {
      const float e_ = eq[q];
      const unsigned u0 = __float_as_uint(xf[0] * e_) + 0x8000u;
      const unsigned u1 = __float_as_uint(xf[1] * e_) + 0x8000u;
      const unsigned u2 = __float_as_uint(xf[2] * e_) + 0x8000u;
      const unsigned u3 = __float_as_uint(xf[3] * e_) + 0x8000u;
      const unsigned u4 = __float_as_uint(xf[4] * e_) + 0x8000u;
      const unsigned u5 = __float_as_uint(xf[5] * e_) + 0x8000u;
      const unsigned u6 = __float_as_uint(xf[6] * e_) + 0x8000u;
      const unsigned u7 = __float_as_uint(xf[7] * e_) + 0x8000u;
      int4v iv;
      iv.x = (int)__builtin_amdgcn_perm(u1, u0, 0x07060302u);
      iv.y = (int)__builtin_amdgcn_perm(u3, u2, 0x07060302u);
      iv.z = (int)__builtin_amdgcn_perm(u5, u4, 0x07060302u);
      iv.w = (int)__builtin_amdgcn_perm(u7, u6, 0x07060302u);
      union { int4v i; bf16x8 h; } cv; cv.i = iv;
      acc = __builtin_amdgcn_mfma_f32_16x16x32_bf16(aq[q], cv.h, acc, 0, 0, 0);
    }

    const float o0 = silu_f(acc[0] * NORM_MSG_TP);
    const float o1 = silu_f(acc[1] * NORM_MSG_TP);
    const float o2 = silu_f(acc[2] * NORM_MSG_TP);
    const float o3 = silu_f(acc[3] * NORM_MSG_TP);
    const unsigned long long wout =
        (unsigned long long)pack_bf16x2(o0, o1) |
        ((unsigned long long)pack_bf16x2(o2, o3) << 32);
    __builtin_nontemporal_store(
        wout, reinterpret_cast<unsigned long long*>(
                  &msgb[(size_t)(t * 16 + el) * 8 + g * 2]));

    cc_a = cc_b; xh_a = xh_b; fa_a = fa_b; fb_a = fb_b;
    cc_b = cc_c;
  }
}

// ---------------- bagg3: bucket-contiguous aggregation, 512 threads ----------------
// bsort reads coalesced across 32 groups; msgb random reads 1-deep pipelined;
// LDS-atomic accumulate into [128][16]; Wlin applied once per node.

__global__ __launch_bounds__(512) void bagg3_kernel(
    const int* __restrict__ boff,     // [NBUK+1]
    const int* __restrict__ bsort,    // [E] packed codes, bucket-contiguous
    const unsigned int* __restrict__ msgb,  // [E*8]
    const float* __restrict__ Wlin,   // [16,16]
    float* __restrict__ agg)          // [N,16]
{
  __shared__ float lagg[128][16];     // 8KB
  __shared__ float sL[256];
  const int t = threadIdx.x;
  const int b = blockIdx.x;           // bucket
  if (t < 256) sL[t] = Wlin[t];
  for (int i = t; i < 2048; i += 512) (&lagg[0][0])[i] = 0.f;
  __syncthreads();

  const int slane = t & 15;
  const int grp   = t >> 4;           // 32 groups
  const int p0 = boff[b];
  const int p1 = boff[b + 1];

  int p = p0 + grp;
  int code_a = (p < p1) ? bsort[p] : 0;
  for (; p < p1; p += 32) {
    const int pn = p + 32;
    const int code_b = (pn < p1) ? bsort[pn] : 0;   // next-iter prefetch
    const unsigned w = msgb[(size_t)(code_a >> 7) * 8 + (slane >> 1)];
    const float v = (slane & 1) ? unhi(w) : unlo(w);
    atomicAdd(&lagg[code_a & 127][slane], v);
    code_a = code_b;
  }
  __syncthreads();

  // agg[node][k2] = NORM_LIN * sum_h lagg[node][h] * Wlin[h][k2]
#pragma unroll
  for (int i = 0; i < 4; ++i) {
    const int idx = t * 4 + i;        // 0..2047
    const int node = idx >> 4, k2 = idx & 15;
    const int n = b * 128 + node;
    if (n < N_NODES_C) {
      float a = 0.f;
#pragma unroll
      for (int h = 0; h < 16; ++h) a = fmaf(lagg[node][h], sL[h * 16 + k2], a);
      agg[(size_t)n * 16 + k2] = a * NORM_LIN;
    }
  }
}

// ---------------- node update ----------------

__global__ __launch_bounds__(256) void node_kernel(
    const float* __restrict__ x, const float* __restrict__ agg,
    const float* __restrict__ Wtp, const float* __restrict__ Wlin,
    float* __restrict__ out)
{
  __shared__ float sW[4096];
  __shared__ float sL[256];
  for (int t = threadIdx.x; t < 4096; t += 256) sW[t] = Wtp[t];
  sL[threadIdx.x] = Wlin[threadIdx.x];
  __syncthreads();

  const long n = (long)blockIdx.x * 256 + threadIdx.x;
  if (n >= N_NODES_C) return;

  float xr[16], ar[16];
  const float4* xp = reinterpret_cast<const float4*>(x + (size_t)n * 16);
  const float4* ap = reinterpret_cast<const float4*>(agg + (size_t)n * 16);
#pragma unroll
  for (int q = 0; q < 4; ++q) {
    float4 v = xp[q];
    xr[q*4+0] = v.x; xr[q*4+1] = v.y; xr[q*4+2] = v.z; xr[q*4+3] = v.w;
    float4 w = ap[q];
    ar[q*4+0] = w.x; ar[q*4+1] = w.y; ar[q*4+2] = w.z; ar[q*4+3] = w.w;
  }
  float u[16];
#pragma unroll
  for (int k = 0; k < 16; ++k) u[k] = 0.f;
#pragma unroll
  for (int i = 0; i < 16; ++i) {
#pragma unroll
    for (int h = 0; h < 16; ++h) {
      const float p = xr[i] * ar[h];
      const float* w = &sW[(i*16 + h) * 16];
#pragma unroll
      for (int k = 0; k < 16; ++k) u[k] = fmaf(p, w[k], u[k]);
    }
  }
  float g[16];
#pragma unroll
  for (int k = 0; k < 16; ++k) g[k] = silu_f(u[k] * NORM_UPD_TP);
  float res[16];
#pragma unroll
  for (int k2 = 0; k2 < 16; ++k2) {
    float a = 0.f;
#pragma unroll
    for (int k = 0; k < 16; ++k) a = fmaf(g[k], sL[k*16 + k2], a);
    res[k2] = xr[k2] + a * NORM_LIN;
  }
  float4* op = reinterpret_cast<float4*>(out + (size_t)n * 16);
#pragma unroll
  for (int q = 0; q < 4; ++q)
    op[q] = make_float4(res[q*4+0], res[q*4+1], res[q*4+2], res[q*4+3]);
}

// ---------------- Tier C fallback: atomic scatter ----------------

__global__ void zero_f4(float4* __restrict__ p, int n4) {
  int i = blockIdx.x * blockDim.x + threadIdx.x;
  if (i < n4) p[i] = make_float4(0.f, 0.f, 0.f, 0.f);
}

#define EPT 2
__global__ __launch_bounds__(256) void edge_kernel(
    const float* __restrict__ x, const float* __restrict__ ea,
    const float* __restrict__ Wtp, const float* __restrict__ Wlin,
    const int* __restrict__ eidx, float* __restrict__ agg)
{
  __shared__ float sW[2048];
  __shared__ float sL[256];
  for (int t = threadIdx.x; t < 2048; t += 256) sW[t] = Wtp[t];
  sL[threadIdx.x] = Wlin[threadIdx.x];
  __syncthreads();
  const long e0 = ((long)blockIdx.x * 256 + threadIdx.x) * EPT;
  float xr[EPT][16], er[EPT][8];
  int rw[EPT];
#pragma unroll
  for (int e = 0; e < EPT; ++e) {
    const long ei = e0 + e;
    const int c = eidx[N_EDGES_C + ei];
    rw[e] = eidx[ei];
    const float4* xp = reinterpret_cast<const float4*>(x + (size_t)c * 16);
#pragma unroll
    for (int q = 0; q < 4; ++q) {
      float4 v = xp[q];
      xr[e][q*4+0] = v.x; xr[e][q*4+1] = v.y; xr[e][q*4+2] = v.z; xr[e][q*4+3] = v.w;
    }
    const float4* ep = reinterpret_cast<const float4*>(ea + (size_t)ei * 8);
#pragma unroll
    for (int q = 0; q < 2; ++q) {
      float4 v = ep[q];
      er[e][q*4+0] = v.x; er[e][q*4+1] = v.y; er[e][q*4+2] = v.z; er[e][q*4+3] = v.w;
    }
  }
  float m[EPT][16];
#pragma unroll
  for (int e = 0; e < EPT; ++e)
#pragma unroll
    for (int h = 0; h < 16; ++h) m[e][h] = 0.f;
#pragma unroll
  for (int i = 0; i < 16; ++i) {
#pragma unroll
    for (int j = 0; j < 8; ++j) {
      float p[EPT];
#pragma unroll
      for (int e = 0; e < EPT; ++e) p[e] = xr[e][i] * er[e][j];
      const float* w = &sW[(i*8 + j) * 16];
#pragma unroll
      for (int h = 0; h < 16; ++h) {
        const float wv = w[h];
#pragma unroll
        for (int e = 0; e < EPT; ++e) m[e][h] = fmaf(p[e], wv, m[e][h]);
      }
    }
  }
#pragma unroll
  for (int e = 0; e < EPT; ++e) {
    float g[16];
#pragma unroll
    for (int h = 0; h < 16; ++h) g[h] = silu_f(m[e][h] * NORM_MSG_TP);
    float* ap = agg + (size_t)rw[e] * 16;
#pragma unroll
    for (int h2 = 0; h2 < 16; ++h2) {
      float a = 0.f;
#pragma unroll
      for (int h = 0; h < 16; ++h) a = fmaf(g[h], sL[h*16 + h2], a);
      atomic_add_hw(ap + h2, a * NORM_LIN);
    }
  }
}

// ---------------- launch ----------------

extern "C" void kernel_launch(void* const* d_in, const int* in_sizes, int n_in,
                              void* d_out, int out_size, void* d_ws, size_t ws_size,
                              hipStream_t stream) {
  const float* node_features = (const float*)d_in[0];
  const float* edge_attr     = (const float*)d_in[1];
  const float* W_msg_tp      = (const float*)d_in[3];
  const float* W_msg_lin     = (const float*)d_in[4];
  const float* W_upd_tp      = (const float*)d_in[5];
  const float* W_upd_lin     = (const float*)d_in[6];
  const int*   edge_index    = (const int*)d_in[7];
  float* out = (float*)d_out;
  char* ws = (char*)d_ws;

  const int NB_N = (N_NODES_C + 255) / 256;           // 391
  const int NB_E = N_EDGES_C / 256;                   // 12500 exact

  // ---- Tier A7: full radix (bucket-contiguous) + edge-order msg + linear bagg ----
  const size_t A_SCT   = 0;                           // 400*784 ints
  const size_t A_COLP  = 1254400;                     // 400*784 ints
  const size_t A_BTOT  = 2508800;                     // 782 ints (pad 3200)
  const size_t A_BOFF  = 2512000;                     // 783 ints (pad 3200)
  const size_t A_BSUM  = 2515200;                     // 512 ints
  const size_t A_BIDS  = 2517248;                     // E ints (12.8 MB); agg aliases
  const size_t A_BSORT = A_BIDS + 12800000;           // E ints (12.8 MB)
  const size_t A_MSGB  = A_BSORT + 12800000;          // E*8 uint (102.4 MB)
  const size_t A_XB    = A_MSGB + 102400000;          // N*16 ushort (3.2 MB)
  const size_t A_NEED  = A_XB + 3200000;              // 133,717,248 B

  if (ws_size >= A_NEED) {
    int* sct   = (int*)(ws + A_SCT);
    int* colp  = (int*)(ws + A_COLP);
    int* btot  = (int*)(ws + A_BTOT);
    int* boff  = (int*)(ws + A_BOFF);
    int* bsum  = (int*)(ws + A_BSUM);
    int* bids  = (int*)(ws + A_BIDS);
    int* bsort = (int*)(ws + A_BSORT);
    unsigned int* msgb = (unsigned int*)(ws + A_MSGB);
    unsigned short* xb = (unsigned short*)(ws + A_XB);
    float* agg = (float*)(ws + A_BIDS);               // alias: bids dead after bscatter

    hipLaunchKernelGGL(bucketize_kernel, dim3(NBLK_BUK), dim3(256), 0, stream,
                       edge_index, bids, sct);
    hipLaunchKernelGGL(colscan_kernel, dim3(NBUK), dim3(256), 0, stream,
                       sct, colp, btot);
    hipLaunchKernelGGL(scan_block, dim3((NBUK + 255) / 256), dim3(256), 0, stream,
                       btot, boff, bsum, NBUK);
    hipLaunchKernelGGL(scan_bsum, dim3(1), dim3(512), 0, stream,
                       bsum, (NBUK + 255) / 256);
    hipLaunchKernelGGL(scan_add, dim3((NBUK + 255) / 256), dim3(256), 0, stream,
                       boff, bsum, NBUK, N_EDGES_C);
    hipLaunchKernelGGL(bscatter_kernel, dim3(NBLK_BUK), dim3(256), 0, stream,
                       bids, sct, colp, boff, bsort);
    hipLaunchKernelGGL(xcast_kernel, dim3((N_NODES_C * 2 + 255) / 256), dim3(256),
                       0, stream, node_features, xb);
    hipLaunchKernelGGL(msg6_kernel, dim3(2048), dim3(256), 0, stream,
                       edge_index, edge_attr, W_msg_tp, xb, msgb);
    hipLaunchKernelGGL(bagg3_kernel, dim3(NBUK), dim3(512), 0, stream,
                       boff, bsort, msgb, W_msg_lin, agg);
    hipLaunchKernelGGL(node_kernel, dim3(NB_N), dim3(256), 0, stream,
                       node_features, agg, W_upd_tp, W_upd_lin, out);
  } else {
    // fallback: atomic scatter path (fits any ws >= 6.4 MB)
    float* agg = (float*)ws;
    const int n4 = N_NODES_C * 16 / 4;
    hipLaunchKernelGGL(zero_f4, dim3((n4 + 255) / 256), dim3(256), 0, stream,
                       (float4*)agg, n4);
    hipLaunchKernelGGL(edge_kernel, dim3(N_EDGES_C / (256 * EPT)), dim3(256), 0, stream,
                       node_features, edge_attr, W_msg_tp, W_msg_lin, edge_index, agg);
    hipLaunchKernelGGL(node_kernel, dim3(NB_N), dim3(256), 0, stream,
                       node_features, agg, W_upd_tp, W_upd_lin, out);
  }
}

// Round 18
// 530.643 us; speedup vs baseline: 1.0237x; 1.0237x over previous
//
#include <hip/hip_runtime.h>
#include <math.h>

#define N_NODES_C 100000
#define N_EDGES_C 3200000
// D_NODE=16, D_EDGE=8, D_HIDDEN=16

#define NORM_MSG_TP 0.08838834764831845f   // 1/sqrt(16*8)
#define NORM_UPD_TP 0.0625f                // 1/sqrt(16*16)
#define NORM_LIN    0.25f                  // 1/sqrt(16)

#define NBUK  782      // buckets of 128 nodes (99999>>7 = 781)
#define NBUKP 784      // padded row
#define BPB   8000     // edges per bucketize block: 3.2M/8000 = 400 exact
#define NBLK_BUK 400

typedef float f32x4 __attribute__((ext_vector_type(4)));
typedef short bf16x8 __attribute__((ext_vector_type(8)));
typedef int   int4v  __attribute__((ext_vector_type(4)));

__device__ __forceinline__ float silu_f(float v) {
  return v / (1.0f + __expf(-v));
}

__device__ __forceinline__ void atomic_add_hw(float* p, float v) {
  unsafeAtomicAdd(p, v);
}

// float -> bf16 bits (round to nearest even)
__device__ __forceinline__ unsigned int bf16_bits(float f) {
  unsigned int b = __float_as_uint(f);
  return (b + 0x7fffu + ((b >> 16) & 1u)) >> 16;
}
__device__ __forceinline__ unsigned int pack_bf16x2(float lo, float hi) {
  return bf16_bits(lo) | (bf16_bits(hi) << 16);
}
__device__ __forceinline__ float unlo(unsigned int w) { return __uint_as_float(w << 16); }
__device__ __forceinline__ float unhi(unsigned int w) { return __uint_as_float(w & 0xffff0000u); }

// ---------------- bucketize: LDS counting-sort by 128-node bucket ----------------

__global__ __launch_bounds__(256) void bucketize_kernel(
    const int* __restrict__ row,
    int* __restrict__ bids,           // [E] packed (eid<<7)|local
    int* __restrict__ sct)            // [NBLK_BUK][NBUKP]
{
  __shared__ int lhist[NBUKP];
  __shared__ int lcur[NBUKP];
  __shared__ int partial[256];
  __shared__ int lids[BPB];
  const int t = threadIdx.x;
  const int base = blockIdx.x * BPB;

  for (int i = t; i < NBUKP; i += 256) lhist[i] = 0;
  __syncthreads();
  for (int k = t; k < BPB; k += 256)
    atomicAdd(&lhist[row[base + k] >> 7], 1);
  __syncthreads();

  int csum = 0;
  if (t < 196) {
    int s = 0;
#pragma unroll
    for (int j = 0; j < 4; ++j) {
      const int v = lhist[t * 4 + j];
      lhist[t * 4 + j] = s;
      s += v;
    }
    csum = s;
  }
  partial[t] = csum;
  __syncthreads();
  for (int o = 1; o < 256; o <<= 1) {
    int tv = (t >= o) ? partial[t - o] : 0;
    __syncthreads();
    partial[t] += tv;
    __syncthreads();
  }
  const int add = partial[t] - csum;
  if (t < 196) {
#pragma unroll
    for (int j = 0; j < 4; ++j) lhist[t * 4 + j] += add;
  }
  __syncthreads();
  for (int i = t; i < NBUKP; i += 256) lcur[i] = lhist[i];
  __syncthreads();

  for (int k = t; k < BPB; k += 256) {
    const int r = row[base + k];
    const int b = r >> 7;
    const int p = atomicAdd(&lcur[b], 1);
    lids[p] = ((base + k) << 7) | (r & 127);
  }
  __syncthreads();

  for (int i = t; i < NBUKP; i += 256)
    sct[blockIdx.x * NBUKP + i] = lhist[i];
  for (int k = t; k < BPB; k += 256)
    bids[base + k] = lids[k];
}

// ---------------- colscan ----------------

__global__ __launch_bounds__(256) void colscan_kernel(
    const int* __restrict__ sct, int* __restrict__ colpre, int* __restrict__ btot) {
  __shared__ int sa[512], sb[512];
  const int t = threadIdx.x;
  const int b = blockIdx.x;
  const int c0 = (t < NBLK_BUK)
      ? sct[t * NBUKP + b + 1] - sct[t * NBUKP + b] : 0;
  const int c1 = (t + 256 < NBLK_BUK)
      ? sct[(t + 256) * NBUKP + b + 1] - sct[(t + 256) * NBUKP + b] : 0;
  sa[t] = c0; sa[t + 256] = c1;
  int* src = sa; int* dst = sb;
  for (int o = 1; o < 512; o <<= 1) {
    __syncthreads();
    dst[t]       = src[t]       + ((t >= o) ? src[t - o] : 0);
    dst[t + 256] = src[t + 256] + ((t + 256 >= o) ? src[t + 256 - o] : 0);
    int* tmp = src; src = dst; dst = tmp;
  }
  __syncthreads();
  if (t < NBLK_BUK) colpre[t * NBUKP + b] = src[t] - c0;
  if (t + 256 < NBLK_BUK) colpre[(t + 256) * NBUKP + b] = src[t + 256] - c1;
  if (t == 0) btot[b] = src[NBLK_BUK - 1];
}

// ---------------- generic scans ----------------

__global__ __launch_bounds__(256) void scan_block(
    const int* __restrict__ cnt, int* __restrict__ off, int* __restrict__ bsum, int n) {
  __shared__ int s[256];
  const int t = threadIdx.x;
  const int i = blockIdx.x * 256 + t;
  const int v = (i < n) ? cnt[i] : 0;
  s[t] = v;
  __syncthreads();
#pragma unroll
  for (int o = 1; o < 256; o <<= 1) {
    int tv = (t >= o) ? s[t - o] : 0;
    __syncthreads();
    s[t] += tv;
    __syncthreads();
  }
  if (i < n) off[i] = s[t] - v;
  if (t == 255) bsum[blockIdx.x] = s[255];
}

__global__ void scan_bsum(int* __restrict__ bsum, int nb) {
  __shared__ int s[512];
  const int t = threadIdx.x;
  const int v = (t < nb) ? bsum[t] : 0;
  s[t] = v;
  __syncthreads();
#pragma unroll
  for (int o = 1; o < 512; o <<= 1) {
    int tv = (t >= o) ? s[t - o] : 0;
    __syncthreads();
    s[t] += tv;
    __syncthreads();
  }
  if (t < nb) bsum[t] = s[t] - v;
}

__global__ __launch_bounds__(256) void scan_add(
    int* __restrict__ off, const int* __restrict__ bsum, int n, int total) {
  int i = blockIdx.x * 256 + threadIdx.x;
  if (i < n) off[i] += bsum[blockIdx.x];
  if (i == 0) off[n] = total;
}

// ---------------- bscatter ----------------

__global__ __launch_bounds__(256) void bscatter_kernel(
    const int* __restrict__ bids, const int* __restrict__ sct,
    const int* __restrict__ colpre, const int* __restrict__ boff,
    int* __restrict__ bsort) {
  __shared__ int srow[NBUKP];
  __shared__ int crow[NBUKP];
  const int t = threadIdx.x;
  const int blk = blockIdx.x;
  for (int i = t; i < NBUKP; i += 256) {
    srow[i] = sct[blk * NBUKP + i];
    crow[i] = colpre[blk * NBUKP + i];
  }
  __syncthreads();
  for (int k = t; k < BPB; k += 256) {
    const int code = bids[blk * BPB + k];
    int lo = 0, hi = 783;
    while (hi - lo > 1) {
      const int mid = (lo + hi) >> 1;
      if (srow[mid] <= k) lo = mid; else hi = mid;
    }
    const int slot = boff[lo] + crow[lo] + (k - srow[lo]);
    bsort[slot] = code;
  }
}

// ---------------- x -> bf16 table ----------------

__global__ __launch_bounds__(256) void xcast_kernel(
    const float* __restrict__ x, unsigned short* __restrict__ xb) {
  const int i = blockIdx.x * 256 + threadIdx.x;
  if (i < N_NODES_C * 2) {
    const float4 a = *reinterpret_cast<const float4*>(x + (size_t)i * 8);
    const float4 b = *reinterpret_cast<const float4*>(x + (size_t)i * 8 + 4);
    uint4 w;
    w.x = pack_bf16x2(a.x, a.y); w.y = pack_bf16x2(a.z, a.w);
    w.z = pack_bf16x2(b.x, b.y); w.w = pack_bf16x2(b.z, b.w);
    *reinterpret_cast<uint4*>(xb + (size_t)i * 8) = w;
  }
}

// ---------------- msg6: swapped-operand MFMA messages, EDGE order, linear nt store ----------------

#define COLS_TILE(T, CC) do {                                        \
    CC = __builtin_nontemporal_load(&eidx[N_EDGES_C + (T) * 16 + el]); \
  } while (0)

#define GATH_TILE(T, CC, XH, FA, FB) do {                            \
    const int e_ = (T) * 16 + el;                                    \
    XH = *reinterpret_cast<const uint4*>(xb + (size_t)(CC) * 16 + 8 * ghalf); \
    FA = __builtin_nontemporal_load(                                 \
        reinterpret_cast<const f32x4*>(ea + (size_t)e_ * 8));        \
    FB = __builtin_nontemporal_load(                                 \
        reinterpret_cast<const f32x4*>(ea + (size_t)e_ * 8 + 4));    \
  } while (0)

__global__ __launch_bounds__(256) void msg6_kernel(
    const int*   __restrict__ eidx,
    const float* __restrict__ ea,
    const float* __restrict__ Wtp,
    const unsigned short* __restrict__ xb,
    unsigned int* __restrict__ msgb)
{
  const int lane  = threadIdx.x & 63;
  const int el    = lane & 15;
  const int g     = lane >> 4;
  const int gsel  = g >> 1;
  const int ghalf = g & 1;

  bf16x8 aq[4];
#pragma unroll
  for (int q = 0; q < 4; ++q) {
#pragma unroll
    for (int t = 0; t < 8; ++t) {
      const float w = Wtp[(8 * ghalf + t) * 128 + (2 * q + gsel) * 16 + el];
      aq[q][t] = (short)bf16_bits(w);
    }
  }

  const int s = gridDim.x * 4;
  const int wid = blockIdx.x * 4 + (threadIdx.x >> 6);
  const int ntiles = N_EDGES_C / 16;

  int cc_a = 0, cc_b = 0;
  uint4 xh_a; xh_a.x = xh_a.y = xh_a.z = xh_a.w = 0;
  f32x4 fa_a = {0.f, 0.f, 0.f, 0.f}, fb_a = {0.f, 0.f, 0.f, 0.f};

  if (wid < ntiles)     COLS_TILE(wid, cc_a);
  if (wid + s < ntiles) COLS_TILE(wid + s, cc_b);
  if (wid < ntiles)     GATH_TILE(wid, cc_a, xh_a, fa_a, fb_a);

  for (int t = wid; t < ntiles; t += s) {
    int cc_c = 0;
    if (t + 2 * s < ntiles) COLS_TILE(t + 2 * s, cc_c);
    uint4 xh_b; xh_b.x = xh_b.y = xh_b.z = xh_b.w = 0;
    f32x4 fa_b = {0.f, 0.f, 0.f, 0.f}, fb_b = {0.f, 0.f, 0.f, 0.f};
    if (t + s < ntiles) GATH_TILE(t + s, cc_b, xh_b, fa_b, fb_b);

    float xf[8];
    xf[0] = unlo(xh_a.x); xf[1] = unhi(xh_a.x);
    xf[2] = unlo(xh_a.y); xf[3] = unhi(xh_a.y);
    xf[4] = unlo(xh_a.z); xf[5] = unhi(xh_a.z);
    xf[6] = unlo(xh_a.w); xf[7] = unhi(xh_a.w);
    float eq[4];
    eq[0] = gsel ? fa_a[1] : fa_a[0];
    eq[1] = gsel ? fa_a[3] : fa_a[2];
    eq[2] = gsel ? fb_a[1] : fb_a[0];
    eq[3] = gsel ? fb_a[3] : fb_a[2];

    f32x4 acc = {0.f, 0.f, 0.f, 0.f};
#pragma unroll
    for (int q = 0; q < 4; ++q) {
      const float e_ = eq[q];
      const unsigned u0 = __float_as_uint(xf[0] * e_) + 0x8000u;
      const unsigned u1 = __float_as_uint(xf[1] * e_) + 0x8000u;
      const unsigned u2 = __float_as_uint(xf[2] * e_) + 0x8000u;
      const unsigned u3 = __float_as_uint(xf[3] * e_) + 0x8000u;
      const unsigned u4 = __float_as_uint(xf[4] * e_) + 0x8000u;
      const unsigned u5 = __float_as_uint(xf[5] * e_) + 0x8000u;
      const unsigned u6 = __float_as_uint(xf[6] * e_) + 0x8000u;
      const unsigned u7 = __float_as_uint(xf[7] * e_) + 0x8000u;
      int4v iv;
      iv.x = (int)__builtin_amdgcn_perm(u1, u0, 0x07060302u);
      iv.y = (int)__builtin_amdgcn_perm(u3, u2, 0x07060302u);
      iv.z = (int)__builtin_amdgcn_perm(u5, u4, 0x07060302u);
      iv.w = (int)__builtin_amdgcn_perm(u7, u6, 0x07060302u);
      union { int4v i; bf16x8 h; } cv; cv.i = iv;
      acc = __builtin_amdgcn_mfma_f32_16x16x32_bf16(aq[q], cv.h, acc, 0, 0, 0);
    }

    const float o0 = silu_f(acc[0] * NORM_MSG_TP);
    const float o1 = silu_f(acc[1] * NORM_MSG_TP);
    const float o2 = silu_f(acc[2] * NORM_MSG_TP);
    const float o3 = silu_f(acc[3] * NORM_MSG_TP);
    const unsigned long long wout =
        (unsigned long long)pack_bf16x2(o0, o1) |
        ((unsigned long long)pack_bf16x2(o2, o3) << 32);
    __builtin_nontemporal_store(
        wout, reinterpret_cast<unsigned long long*>(
                  &msgb[(size_t)(t * 16 + el) * 8 + g * 2]));

    cc_a = cc_b; xh_a = xh_b; fa_a = fa_b; fb_a = fb_b;
    cc_b = cc_c;
  }
}

// ---------------- bagg4: 3-deep pipelined bucket aggregation ----------------
// Codes c0/c1/c2 live; msgb words w0 (consume) and w1 (in flight) rotate; each
// iteration issues the load for c2 before the atomic consuming w0 -> 2-3 random
// loads in flight per group (x32 groups x8 waves = saturating MLP).
// lagg rows padded to 17 floats (bank-spread).

__global__ __launch_bounds__(512) void bagg4_kernel(
    const int* __restrict__ boff,     // [NBUK+1]
    const int* __restrict__ bsort,    // [E]
    const unsigned int* __restrict__ msgb,  // [E*8]
    const float* __restrict__ Wlin,   // [16,16]
    float* __restrict__ agg)          // [N,16]
{
  __shared__ float lagg[128][17];     // 8.5KB, padded
  __shared__ float sL[256];
  const int t = threadIdx.x;
  const int b = blockIdx.x;
  if (t < 256) sL[t] = Wlin[t];
  for (int i = t; i < 128 * 17; i += 512) (&lagg[0][0])[i] = 0.f;
  __syncthreads();

  const int slane = t & 15;
  const int wsel  = slane >> 1;
  const int grp   = t >> 4;           // 32 groups
  const int p0 = boff[b];
  const int p1 = boff[b + 1];

  int p = p0 + grp;
  int c0 = (p < p1) ? bsort[p] : -1;
  int c1 = (p + 32 < p1) ? bsort[p + 32] : -1;
  unsigned w0 = (c0 >= 0) ? msgb[(size_t)(c0 >> 7) * 8 + wsel] : 0;
  unsigned w1 = (c1 >= 0) ? msgb[(size_t)(c1 >> 7) * 8 + wsel] : 0;

  for (; p < p1; p += 32) {
    const int c2 = (p + 64 < p1) ? bsort[p + 64] : -1;
    const unsigned w2 = (c2 >= 0) ? msgb[(size_t)(c2 >> 7) * 8 + wsel] : 0;
    const float v = (slane & 1) ? unhi(w0) : unlo(w0);
    atomicAdd(&lagg[c0 & 127][slane], v);
    c0 = c1; c1 = c2; w0 = w1; w1 = w2;
  }
  __syncthreads();

  // agg[node][k2] = NORM_LIN * sum_h lagg[node][h] * Wlin[h][k2]
#pragma unroll
  for (int i = 0; i < 4; ++i) {
    const int idx = t * 4 + i;        // 0..2047
    const int node = idx >> 4, k2 = idx & 15;
    const int n = b * 128 + node;
    if (n < N_NODES_C) {
      float a = 0.f;
#pragma unroll
      for (int h = 0; h < 16; ++h) a = fmaf(lagg[node][h], sL[h * 16 + k2], a);
      agg[(size_t)n * 16 + k2] = a * NORM_LIN;
    }
  }
}

// ---------------- node update ----------------

__global__ __launch_bounds__(256) void node_kernel(
    const float* __restrict__ x, const float* __restrict__ agg,
    const float* __restrict__ Wtp, const float* __restrict__ Wlin,
    float* __restrict__ out)
{
  __shared__ float sW[4096];
  __shared__ float sL[256];
  for (int t = threadIdx.x; t < 4096; t += 256) sW[t] = Wtp[t];
  sL[threadIdx.x] = Wlin[threadIdx.x];
  __syncthreads();

  const long n = (long)blockIdx.x * 256 + threadIdx.x;
  if (n >= N_NODES_C) return;

  float xr[16], ar[16];
  const float4* xp = reinterpret_cast<const float4*>(x + (size_t)n * 16);
  const float4* ap = reinterpret_cast<const float4*>(agg + (size_t)n * 16);
#pragma unroll
  for (int q = 0; q < 4; ++q) {
    float4 v = xp[q];
    xr[q*4+0] = v.x; xr[q*4+1] = v.y; xr[q*4+2] = v.z; xr[q*4+3] = v.w;
    float4 w = ap[q];
    ar[q*4+0] = w.x; ar[q*4+1] = w.y; ar[q*4+2] = w.z; ar[q*4+3] = w.w;
  }
  float u[16];
#pragma unroll
  for (int k = 0; k < 16; ++k) u[k] = 0.f;
#pragma unroll
  for (int i = 0; i < 16; ++i) {
#pragma unroll
    for (int h = 0; h < 16; ++h) {
      const float p = xr[i] * ar[h];
      const float* w = &sW[(i*16 + h) * 16];
#pragma unroll
      for (int k = 0; k < 16; ++k) u[k] = fmaf(p, w[k], u[k]);
    }
  }
  float g[16];
#pragma unroll
  for (int k = 0; k < 16; ++k) g[k] = silu_f(u[k] * NORM_UPD_TP);
  float res[16];
#pragma unroll
  for (int k2 = 0; k2 < 16; ++k2) {
    float a = 0.f;
#pragma unroll
    for (int k = 0; k < 16; ++k) a = fmaf(g[k], sL[k*16 + k2], a);
    res[k2] = xr[k2] + a * NORM_LIN;
  }
  float4* op = reinterpret_cast<float4*>(out + (size_t)n * 16);
#pragma unroll
  for (int q = 0; q < 4; ++q)
    op[q] = make_float4(res[q*4+0], res[q*4+1], res[q*4+2], res[q*4+3]);
}

// ---------------- Tier C fallback: atomic scatter ----------------

__global__ void zero_f4(float4* __restrict__ p, int n4) {
  int i = blockIdx.x * blockDim.x + threadIdx.x;
  if (i < n4) p[i] = make_float4(0.f, 0.f, 0.f, 0.f);
}

#define EPT 2
__global__ __launch_bounds__(256) void edge_kernel(
    const float* __restrict__ x, const float* __restrict__ ea,
    const float* __restrict__ Wtp, const float* __restrict__ Wlin,
    const int* __restrict__ eidx, float* __restrict__ agg)
{
  __shared__ float sW[2048];
  __shared__ float sL[256];
  for (int t = threadIdx.x; t < 2048; t += 256) sW[t] = Wtp[t];
  sL[threadIdx.x] = Wlin[threadIdx.x];
  __syncthreads();
  const long e0 = ((long)blockIdx.x * 256 + threadIdx.x) * EPT;
  float xr[EPT][16], er[EPT][8];
  int rw[EPT];
#pragma unroll
  for (int e = 0; e < EPT; ++e) {
    const long ei = e0 + e;
    const int c = eidx[N_EDGES_C + ei];
    rw[e] = eidx[ei];
    const float4* xp = reinterpret_cast<const float4*>(x + (size_t)c * 16);
#pragma unroll
    for (int q = 0; q < 4; ++q) {
      float4 v = xp[q];
      xr[e][q*4+0] = v.x; xr[e][q*4+1] = v.y; xr[e][q*4+2] = v.z; xr[e][q*4+3] = v.w;
    }
    const float4* ep = reinterpret_cast<const float4*>(ea + (size_t)ei * 8);
#pragma unroll
    for (int q = 0; q < 2; ++q) {
      float4 v = ep[q];
      er[e][q*4+0] = v.x; er[e][q*4+1] = v.y; er[e][q*4+2] = v.z; er[e][q*4+3] = v.w;
    }
  }
  float m[EPT][16];
#pragma unroll
  for (int e = 0; e < EPT; ++e)
#pragma unroll
    for (int h = 0; h < 16; ++h) m[e][h] = 0.f;
#pragma unroll
  for (int i = 0; i < 16; ++i) {
#pragma unroll
    for (int j = 0; j < 8; ++j) {
      float p[EPT];
#pragma unroll
      for (int e = 0; e < EPT; ++e) p[e] = xr[e][i] * er[e][j];
      const float* w = &sW[(i*8 + j) * 16];
#pragma unroll
      for (int h = 0; h < 16; ++h) {
        const float wv = w[h];
#pragma unroll
        for (int e = 0; e < EPT; ++e) m[e][h] = fmaf(p[e], wv, m[e][h]);
      }
    }
  }
#pragma unroll
  for (int e = 0; e < EPT; ++e) {
    float g[16];
#pragma unroll
    for (int h = 0; h < 16; ++h) g[h] = silu_f(m[e][h] * NORM_MSG_TP);
    float* ap = agg + (size_t)rw[e] * 16;
#pragma unroll
    for (int h2 = 0; h2 < 16; ++h2) {
      float a = 0.f;
#pragma unroll
      for (int h = 0; h < 16; ++h) a = fmaf(g[h], sL[h*16 + h2], a);
      atomic_add_hw(ap + h2, a * NORM_LIN);
    }
  }
}

// ---------------- launch ----------------

extern "C" void kernel_launch(void* const* d_in, const int* in_sizes, int n_in,
                              void* d_out, int out_size, void* d_ws, size_t ws_size,
                              hipStream_t stream) {
  const float* node_features = (const float*)d_in[0];
  const float* edge_attr     = (const float*)d_in[1];
  const float* W_msg_tp      = (const float*)d_in[3];
  const float* W_msg_lin     = (const float*)d_in[4];
  const float* W_upd_tp      = (const float*)d_in[5];
  const float* W_upd_lin     = (const float*)d_in[6];
  const int*   edge_index    = (const int*)d_in[7];
  float* out = (float*)d_out;
  char* ws = (char*)d_ws;

  const int NB_N = (N_NODES_C + 255) / 256;           // 391
  const int NB_E = N_EDGES_C / 256;                   // 12500 exact

  // ---- Tier A8: radix + edge-order msg + 3-deep pipelined bagg ----
  const size_t A_SCT   = 0;                           // 400*784 ints
  const size_t A_COLP  = 1254400;                     // 400*784 ints
  const size_t A_BTOT  = 2508800;                     // 782 ints (pad 3200)
  const size_t A_BOFF  = 2512000;                     // 783 ints (pad 3200)
  const size_t A_BSUM  = 2515200;                     // 512 ints
  const size_t A_BIDS  = 2517248;                     // E ints (12.8 MB); agg aliases
  const size_t A_BSORT = A_BIDS + 12800000;           // E ints (12.8 MB)
  const size_t A_MSGB  = A_BSORT + 12800000;          // E*8 uint (102.4 MB)
  const size_t A_XB    = A_MSGB + 102400000;          // N*16 ushort (3.2 MB)
  const size_t A_NEED  = A_XB + 3200000;              // 133,717,248 B

  if (ws_size >= A_NEED) {
    int* sct   = (int*)(ws + A_SCT);
    int* colp  = (int*)(ws + A_COLP);
    int* btot  = (int*)(ws + A_BTOT);
    int* boff  = (int*)(ws + A_BOFF);
    int* bsum  = (int*)(ws + A_BSUM);
    int* bids  = (int*)(ws + A_BIDS);
    int* bsort = (int*)(ws + A_BSORT);
    unsigned int* msgb = (unsigned int*)(ws + A_MSGB);
    unsigned short* xb = (unsigned short*)(ws + A_XB);
    float* agg = (float*)(ws + A_BIDS);               // alias: bids dead after bscatter

    hipLaunchKernelGGL(bucketize_kernel, dim3(NBLK_BUK), dim3(256), 0, stream,
                       edge_index, bids, sct);
    hipLaunchKernelGGL(colscan_kernel, dim3(NBUK), dim3(256), 0, stream,
                       sct, colp, btot);
    hipLaunchKernelGGL(scan_block, dim3((NBUK + 255) / 256), dim3(256), 0, stream,
                       btot, boff, bsum, NBUK);
    hipLaunchKernelGGL(scan_bsum, dim3(1), dim3(512), 0, stream,
                       bsum, (NBUK + 255) / 256);
    hipLaunchKernelGGL(scan_add, dim3((NBUK + 255) / 256), dim3(256), 0, stream,
                       boff, bsum, NBUK, N_EDGES_C);
    hipLaunchKernelGGL(bscatter_kernel, dim3(NBLK_BUK), dim3(256), 0, stream,
                       bids, sct, colp, boff, bsort);
    hipLaunchKernelGGL(xcast_kernel, dim3((N_NODES_C * 2 + 255) / 256), dim3(256),
                       0, stream, node_features, xb);
    hipLaunchKernelGGL(msg6_kernel, dim3(2048), dim3(256), 0, stream,
                       edge_index, edge_attr, W_msg_tp, xb, msgb);
    hipLaunchKernelGGL(bagg4_kernel, dim3(NBUK), dim3(512), 0, stream,
                       boff, bsort, msgb, W_msg_lin, agg);
    hipLaunchKernelGGL(node_kernel, dim3(NB_N), dim3(256), 0, stream,
                       node_features, agg, W_upd_tp, W_upd_lin, out);
  } else {
    float* agg = (float*)ws;
    const int n4 = N_NODES_C * 16 / 4;
    hipLaunchKernelGGL(zero_f4, dim3((n4 + 255) / 256), dim3(256), 0, stream,
                       (float4*)agg, n4);
    hipLaunchKernelGGL(edge_kernel, dim3(N_EDGES_C / (256 * EPT)), dim3(256), 0, stream,
                       node_features, edge_attr, W_msg_tp, W_msg_lin, edge_index, agg);
    hipLaunchKernelGGL(node_kernel, dim3(NB_N), dim3(256), 0, stream,
                       node_features, agg, W_upd_tp, W_upd_lin, out);
  }
}

// Round 19
// 493.746 us; speedup vs baseline: 1.1002x; 1.0747x over previous
//
#include <hip/hip_runtime.h>
#include <math.h>

#define N_NODES_C 100000
#define N_EDGES_C 3200000
// D_NODE=16, D_EDGE=8, D_HIDDEN=16

#define NORM_MSG_TP 0.08838834764831845f   // 1/sqrt(16*8)
#define NORM_UPD_TP 0.0625f                // 1/sqrt(16*16)
#define NORM_LIN    0.25f                  // 1/sqrt(16)

#define NBUK  782      // buckets of 128 nodes
#define NBUKP 784
#define BPB   8000     // edges per bucketize block: 3.2M/8000 = 400 exact
#define NBLK_BUK 400

typedef float f32x4 __attribute__((ext_vector_type(4)));
typedef short bf16x8 __attribute__((ext_vector_type(8)));
typedef int   int4v  __attribute__((ext_vector_type(4)));

__device__ __forceinline__ float silu_f(float v) {
  return v / (1.0f + __expf(-v));
}

__device__ __forceinline__ void atomic_add_hw(float* p, float v) {
  unsafeAtomicAdd(p, v);
}

__device__ __forceinline__ unsigned int bf16_bits(float f) {
  unsigned int b = __float_as_uint(f);
  return (b + 0x7fffu + ((b >> 16) & 1u)) >> 16;
}
__device__ __forceinline__ unsigned int pack_bf16x2(float lo, float hi) {
  return bf16_bits(lo) | (bf16_bits(hi) << 16);
}
__device__ __forceinline__ float unlo(unsigned int w) { return __uint_as_float(w << 16); }
__device__ __forceinline__ float unhi(unsigned int w) { return __uint_as_float(w & 0xffff0000u); }

// ---------------- bucketize ----------------

__global__ __launch_bounds__(256) void bucketize_kernel(
    const int* __restrict__ row,
    int* __restrict__ bids,           // [E] (eid<<7)|local, bucket-grouped per block
    int* __restrict__ sct)            // [NBLK_BUK][NBUKP]
{
  __shared__ int lhist[NBUKP];
  __shared__ int lcur[NBUKP];
  __shared__ int partial[256];
  __shared__ int lids[BPB];
  const int t = threadIdx.x;
  const int base = blockIdx.x * BPB;

  for (int i = t; i < NBUKP; i += 256) lhist[i] = 0;
  __syncthreads();
  for (int k = t; k < BPB; k += 256)
    atomicAdd(&lhist[row[base + k] >> 7], 1);
  __syncthreads();

  int csum = 0;
  if (t < 196) {
    int s = 0;
#pragma unroll
    for (int j = 0; j < 4; ++j) {
      const int v = lhist[t * 4 + j];
      lhist[t * 4 + j] = s;
      s += v;
    }
    csum = s;
  }
  partial[t] = csum;
  __syncthreads();
  for (int o = 1; o < 256; o <<= 1) {
    int tv = (t >= o) ? partial[t - o] : 0;
    __syncthreads();
    partial[t] += tv;
    __syncthreads();
  }
  const int add = partial[t] - csum;
  if (t < 196) {
#pragma unroll
    for (int j = 0; j < 4; ++j) lhist[t * 4 + j] += add;
  }
  __syncthreads();
  for (int i = t; i < NBUKP; i += 256) lcur[i] = lhist[i];
  __syncthreads();

  for (int k = t; k < BPB; k += 256) {
    const int r = row[base + k];
    const int b = r >> 7;
    const int p = atomicAdd(&lcur[b], 1);
    lids[p] = ((base + k) << 7) | (r & 127);
  }
  __syncthreads();

  for (int i = t; i < NBUKP; i += 256)
    sct[blockIdx.x * NBUKP + i] = lhist[i];
  for (int k = t; k < BPB; k += 256)
    bids[base + k] = lids[k];
}

// ---------------- colscan ----------------

__global__ __launch_bounds__(256) void colscan_kernel(
    const int* __restrict__ sct, int* __restrict__ colpre, int* __restrict__ btot) {
  __shared__ int sa[512], sb[512];
  const int t = threadIdx.x;
  const int b = blockIdx.x;
  const int c0 = (t < NBLK_BUK)
      ? sct[t * NBUKP + b + 1] - sct[t * NBUKP + b] : 0;
  const int c1 = (t + 256 < NBLK_BUK)
      ? sct[(t + 256) * NBUKP + b + 1] - sct[(t + 256) * NBUKP + b] : 0;
  sa[t] = c0; sa[t + 256] = c1;
  int* src = sa; int* dst = sb;
  for (int o = 1; o < 512; o <<= 1) {
    __syncthreads();
    dst[t]       = src[t]       + ((t >= o) ? src[t - o] : 0);
    dst[t + 256] = src[t + 256] + ((t + 256 >= o) ? src[t + 256 - o] : 0);
    int* tmp = src; src = dst; dst = tmp;
  }
  __syncthreads();
  if (t < NBLK_BUK) colpre[t * NBUKP + b] = src[t] - c0;
  if (t + 256 < NBLK_BUK) colpre[(t + 256) * NBUKP + b] = src[t + 256] - c1;
  if (t == 0) btot[b] = src[NBLK_BUK - 1];
}

// ---------------- generic scans ----------------

__global__ __launch_bounds__(256) void scan_block(
    const int* __restrict__ cnt, int* __restrict__ off, int* __restrict__ bsum, int n) {
  __shared__ int s[256];
  const int t = threadIdx.x;
  const int i = blockIdx.x * 256 + t;
  const int v = (i < n) ? cnt[i] : 0;
  s[t] = v;
  __syncthreads();
#pragma unroll
  for (int o = 1; o < 256; o <<= 1) {
    int tv = (t >= o) ? s[t - o] : 0;
    __syncthreads();
    s[t] += tv;
    __syncthreads();
  }
  if (i < n) off[i] = s[t] - v;
  if (t == 255) bsum[blockIdx.x] = s[255];
}

__global__ void scan_bsum(int* __restrict__ bsum, int nb) {
  __shared__ int s[512];
  const int t = threadIdx.x;
  const int v = (t < nb) ? bsum[t] : 0;
  s[t] = v;
  __syncthreads();
#pragma unroll
  for (int o = 1; o < 512; o <<= 1) {
    int tv = (t >= o) ? s[t - o] : 0;
    __syncthreads();
    s[t] += tv;
    __syncthreads();
  }
  if (t < nb) bsum[t] = s[t] - v;
}

__global__ __launch_bounds__(256) void scan_add(
    int* __restrict__ off, const int* __restrict__ bsum, int n, int total) {
  int i = blockIdx.x * 256 + threadIdx.x;
  if (i < n) off[i] += bsum[blockIdx.x];
  if (i == 0) off[n] = total;
}

// ---------------- bscatter2: carry (local|col) + bf16-ea to sorted slots ----------------
// Random reads (eidx col / ea) stay inside this block's 8000-edge window
// (32KB / 256KB -> L2-resident). Stores land in ~10-slot runs (semi-coalesced).

__global__ __launch_bounds__(256) void bscatter2_kernel(
    const int* __restrict__ bids, const int* __restrict__ sct,
    const int* __restrict__ colpre, const int* __restrict__ boff,
    const int* __restrict__ eidx, const float* __restrict__ ea,
    int* __restrict__ cl, uint4* __restrict__ eab) {
  __shared__ int srow[NBUKP];
  __shared__ int crow[NBUKP];
  const int t = threadIdx.x;
  const int blk = blockIdx.x;
  for (int i = t; i < NBUKP; i += 256) {
    srow[i] = sct[blk * NBUKP + i];
    crow[i] = colpre[blk * NBUKP + i];
  }
  __syncthreads();
  for (int k = t; k < BPB; k += 256) {
    const int code = bids[blk * BPB + k];
    const int eid = code >> 7;
    const int local = code & 127;
    int lo = 0, hi = 783;
    while (hi - lo > 1) {
      const int mid = (lo + hi) >> 1;
      if (srow[mid] <= k) lo = mid; else hi = mid;
    }
    const int slot = boff[lo] + crow[lo] + (k - srow[lo]);
    const int col = eidx[N_EDGES_C + eid];            // 32KB window, L2
    cl[slot] = (local << 20) | col;                   // col < 2^20
    const float4 a = *reinterpret_cast<const float4*>(ea + (size_t)eid * 8);
    const float4 b = *reinterpret_cast<const float4*>(ea + (size_t)eid * 8 + 4);
    uint4 w;
    w.x = pack_bf16x2(a.x, a.y);
    w.y = pack_bf16x2(a.z, a.w);
    w.z = pack_bf16x2(b.x, b.y);
    w.w = pack_bf16x2(b.z, b.w);
    eab[slot] = w;
  }
}

// ---------------- x -> bf16 table ----------------

__global__ __launch_bounds__(256) void xcast_kernel(
    const float* __restrict__ x, unsigned short* __restrict__ xb) {
  const int i = blockIdx.x * 256 + threadIdx.x;
  if (i < N_NODES_C * 2) {
    const float4 a = *reinterpret_cast<const float4*>(x + (size_t)i * 8);
    const float4 b = *reinterpret_cast<const float4*>(x + (size_t)i * 8 + 4);
    uint4 w;
    w.x = pack_bf16x2(a.x, a.y); w.y = pack_bf16x2(a.z, a.w);
    w.z = pack_bf16x2(b.x, b.y); w.w = pack_bf16x2(b.z, b.w);
    *reinterpret_cast<uint4*>(xb + (size_t)i * 8) = w;
  }
}

// ---------------- bagg5: fused sorted-order MFMA message + LDS aggregation ----------------
// One block per bucket, 8 waves. Wave tile = 16 sorted slots: cl (64B) and eab
// (256B) stream linearly; xb[col] gathers hit the L2-resident 3.2MB table.
// Swapped-operand MFMA (lane el = edge, rows = h quad) -> silu -> 4 LDS
// atomicAdds into lagg[local][.]; Wlin once per node at the end.

__global__ __launch_bounds__(512) void bagg5_kernel(
    const int* __restrict__ boff,     // [NBUK+1]
    const int* __restrict__ cl,       // [E] (local<<20)|col at sorted slot
    const uint4* __restrict__ eab,    // [E] bf16x8 ea at sorted slot
    const unsigned short* __restrict__ xb,  // [N,16] bf16
    const float* __restrict__ Wtp,    // [16,8,16]
    const float* __restrict__ Wlin,   // [16,16]
    float* __restrict__ agg)          // [N,16]
{
  __shared__ float lagg[128][17];
  __shared__ float sL[256];
  const int t = threadIdx.x;
  const int b = blockIdx.x;
  if (t < 256) sL[t] = Wlin[t];
  for (int i = t; i < 128 * 17; i += 512) (&lagg[0][0])[i] = 0.f;
  __syncthreads();

  const int lane  = t & 63;
  const int wv    = t >> 6;           // 8 waves
  const int el    = lane & 15;
  const int g     = lane >> 4;
  const int gsel  = g >> 1;
  const int ghalf = g & 1;

  // A frag (constant W): aq[q][tt] = Wtp[i=8*ghalf+tt][j=2q+gsel][h=el] (k=j*16+i)
  bf16x8 aq[4];
#pragma unroll
  for (int q = 0; q < 4; ++q) {
#pragma unroll
    for (int tt = 0; tt < 8; ++tt) {
      const float w = Wtp[(8 * ghalf + tt) * 128 + (2 * q + gsel) * 16 + el];
      aq[q][tt] = (short)bf16_bits(w);
    }
  }

  const int p0 = boff[b];
  const int p1 = boff[b + 1];

  for (int sbase = p0 + wv * 16; sbase < p1; sbase += 8 * 16) {
    const int s = sbase + el;
    const bool ok = (s < p1);
    const int clv = ok ? cl[s] : 0;
    const int col = clv & 0xFFFFF;
    const int local = clv >> 20;
    uint4 ev;
    if (ok) ev = eab[s];
    else { ev.x = ev.y = ev.z = ev.w = 0; }
    const uint4 xh = *reinterpret_cast<const uint4*>(
        xb + (size_t)col * 16 + 8 * ghalf);

    float xf[8];
    xf[0] = unlo(xh.x); xf[1] = unhi(xh.x);
    xf[2] = unlo(xh.y); xf[3] = unhi(xh.y);
    xf[4] = unlo(xh.z); xf[5] = unhi(xh.z);
    xf[6] = unlo(xh.w); xf[7] = unhi(xh.w);
    float eq[4];
    eq[0] = gsel ? unhi(ev.x) : unlo(ev.x);
    eq[1] = gsel ? unhi(ev.y) : unlo(ev.y);
    eq[2] = gsel ? unhi(ev.z) : unlo(ev.z);
    eq[3] = gsel ? unhi(ev.w) : unlo(ev.w);

    f32x4 acc = {0.f, 0.f, 0.f, 0.f};
#pragma unroll
    for (int q = 0; q < 4; ++q) {
      const float e_ = eq[q];
      const unsigned u0 = __float_as_uint(xf[0] * e_) + 0x8000u;
      const unsigned u1 = __float_as_uint(xf[1] * e_) + 0x8000u;
      const unsigned u2 = __float_as_uint(xf[2] * e_) + 0x8000u;
      const unsigned u3 = __float_as_uint(xf[3] * e_) + 0x8000u;
      const unsigned u4 = __float_as_uint(xf[4] * e_) + 0x8000u;
      const unsigned u5 = __float_as_uint(xf[5] * e_) + 0x8000u;
      const unsigned u6 = __float_as_uint(xf[6] * e_) + 0x8000u;
      const unsigned u7 = __float_as_uint(xf[7] * e_) + 0x8000u;
      int4v iv;
      iv.x = (int)__builtin_amdgcn_perm(u1, u0, 0x07060302u);
      iv.y = (int)__builtin_amdgcn_perm(u3, u2, 0x07060302u);
      iv.z = (int)__builtin_amdgcn_perm(u5, u4, 0x07060302u);
      iv.w = (int)__builtin_amdgcn_perm(u7, u6, 0x07060302u);
      union { int4v i; bf16x8 h; } cv; cv.i = iv;
      acc = __builtin_amdgcn_mfma_f32_16x16x32_bf16(aq[q], cv.h, acc, 0, 0, 0);
    }

    if (ok) {
      atomicAdd(&lagg[local][4 * g + 0], silu_f(acc[0] * NORM_MSG_TP));
      atomicAdd(&lagg[local][4 * g + 1], silu_f(acc[1] * NORM_MSG_TP));
      atomicAdd(&lagg[local][4 * g + 2], silu_f(acc[2] * NORM_MSG_TP));
      atomicAdd(&lagg[local][4 * g + 3], silu_f(acc[3] * NORM_MSG_TP));
    }
  }
  __syncthreads();

  // agg[node][k2] = NORM_LIN * sum_h lagg[node][h] * Wlin[h][k2]
#pragma unroll
  for (int i = 0; i < 4; ++i) {
    const int idx = t * 4 + i;        // 0..2047
    const int node = idx >> 4, k2 = idx & 15;
    const int n = b * 128 + node;
    if (n < N_NODES_C) {
      float a = 0.f;
#pragma unroll
      for (int h = 0; h < 16; ++h) a = fmaf(lagg[node][h], sL[h * 16 + k2], a);
      agg[(size_t)n * 16 + k2] = a * NORM_LIN;
    }
  }
}

// ---------------- node update ----------------

__global__ __launch_bounds__(256) void node_kernel(
    const float* __restrict__ x, const float* __restrict__ agg,
    const float* __restrict__ Wtp, const float* __restrict__ Wlin,
    float* __restrict__ out)
{
  __shared__ float sW[4096];
  __shared__ float sL[256];
  for (int t = threadIdx.x; t < 4096; t += 256) sW[t] = Wtp[t];
  sL[threadIdx.x] = Wlin[threadIdx.x];
  __syncthreads();

  const long n = (long)blockIdx.x * 256 + threadIdx.x;
  if (n >= N_NODES_C) return;

  float xr[16], ar[16];
  const float4* xp = reinterpret_cast<const float4*>(x + (size_t)n * 16);
  const float4* ap = reinterpret_cast<const float4*>(agg + (size_t)n * 16);
#pragma unroll
  for (int q = 0; q < 4; ++q) {
    float4 v = xp[q];
    xr[q*4+0] = v.x; xr[q*4+1] = v.y; xr[q*4+2] = v.z; xr[q*4+3] = v.w;
    float4 w = ap[q];
    ar[q*4+0] = w.x; ar[q*4+1] = w.y; ar[q*4+2] = w.z; ar[q*4+3] = w.w;
  }
  float u[16];
#pragma unroll
  for (int k = 0; k < 16; ++k) u[k] = 0.f;
#pragma unroll
  for (int i = 0; i < 16; ++i) {
#pragma unroll
    for (int h = 0; h < 16; ++h) {
      const float p = xr[i] * ar[h];
      const float* w = &sW[(i*16 + h) * 16];
#pragma unroll
      for (int k = 0; k < 16; ++k) u[k] = fmaf(p, w[k], u[k]);
    }
  }
  float g[16];
#pragma unroll
  for (int k = 0; k < 16; ++k) g[k] = silu_f(u[k] * NORM_UPD_TP);
  float res[16];
#pragma unroll
  for (int k2 = 0; k2 < 16; ++k2) {
    float a = 0.f;
#pragma unroll
    for (int k = 0; k < 16; ++k) a = fmaf(g[k], sL[k*16 + k2], a);
    res[k2] = xr[k2] + a * NORM_LIN;
  }
  float4* op = reinterpret_cast<float4*>(out + (size_t)n * 16);
#pragma unroll
  for (int q = 0; q < 4; ++q)
    op[q] = make_float4(res[q*4+0], res[q*4+1], res[q*4+2], res[q*4+3]);
}

// ---------------- Tier C fallback: atomic scatter ----------------

__global__ void zero_f4(float4* __restrict__ p, int n4) {
  int i = blockIdx.x * blockDim.x + threadIdx.x;
  if (i < n4) p[i] = make_float4(0.f, 0.f, 0.f, 0.f);
}

#define EPT 2
__global__ __launch_bounds__(256) void edge_kernel(
    const float* __restrict__ x, const float* __restrict__ ea,
    const float* __restrict__ Wtp, const float* __restrict__ Wlin,
    const int* __restrict__ eidx, float* __restrict__ agg)
{
  __shared__ float sW[2048];
  __shared__ float sL[256];
  for (int t = threadIdx.x; t < 2048; t += 256) sW[t] = Wtp[t];
  sL[threadIdx.x] = Wlin[threadIdx.x];
  __syncthreads();
  const long e0 = ((long)blockIdx.x * 256 + threadIdx.x) * EPT;
  float xr[EPT][16], er[EPT][8];
  int rw[EPT];
#pragma unroll
  for (int e = 0; e < EPT; ++e) {
    const long ei = e0 + e;
    const int c = eidx[N_EDGES_C + ei];
    rw[e] = eidx[ei];
    const float4* xp = reinterpret_cast<const float4*>(x + (size_t)c * 16);
#pragma unroll
    for (int q = 0; q < 4; ++q) {
      float4 v = xp[q];
      xr[e][q*4+0] = v.x; xr[e][q*4+1] = v.y; xr[e][q*4+2] = v.z; xr[e][q*4+3] = v.w;
    }
    const float4* ep = reinterpret_cast<const float4*>(ea + (size_t)ei * 8);
#pragma unroll
    for (int q = 0; q < 2; ++q) {
      float4 v = ep[q];
      er[e][q*4+0] = v.x; er[e][q*4+1] = v.y; er[e][q*4+2] = v.z; er[e][q*4+3] = v.w;
    }
  }
  float m[EPT][16];
#pragma unroll
  for (int e = 0; e < EPT; ++e)
#pragma unroll
    for (int h = 0; h < 16; ++h) m[e][h] = 0.f;
#pragma unroll
  for (int i = 0; i < 16; ++i) {
#pragma unroll
    for (int j = 0; j < 8; ++j) {
      float p[EPT];
#pragma unroll
      for (int e = 0; e < EPT; ++e) p[e] = xr[e][i] * er[e][j];
      const float* w = &sW[(i*8 + j) * 16];
#pragma unroll
      for (int h = 0; h < 16; ++h) {
        const float wv = w[h];
#pragma unroll
        for (int e = 0; e < EPT; ++e) m[e][h] = fmaf(p[e], wv, m[e][h]);
      }
    }
  }
#pragma unroll
  for (int e = 0; e < EPT; ++e) {
    float g[16];
#pragma unroll
    for (int h = 0; h < 16; ++h) g[h] = silu_f(m[e][h] * NORM_MSG_TP);
    float* ap = agg + (size_t)rw[e] * 16;
#pragma unroll
    for (int h2 = 0; h2 < 16; ++h2) {
      float a = 0.f;
#pragma unroll
      for (int h = 0; h < 16; ++h) a = fmaf(g[h], sL[h*16 + h2], a);
      atomic_add_hw(ap + h2, a * NORM_LIN);
    }
  }
}

// ---------------- launch ----------------

extern "C" void kernel_launch(void* const* d_in, const int* in_sizes, int n_in,
                              void* d_out, int out_size, void* d_ws, size_t ws_size,
                              hipStream_t stream) {
  const float* node_features = (const float*)d_in[0];
  const float* edge_attr     = (const float*)d_in[1];
  const float* W_msg_tp      = (const float*)d_in[3];
  const float* W_msg_lin     = (const float*)d_in[4];
  const float* W_upd_tp      = (const float*)d_in[5];
  const float* W_upd_lin     = (const float*)d_in[6];
  const int*   edge_index    = (const int*)d_in[7];
  float* out = (float*)d_out;
  char* ws = (char*)d_ws;

  const int NB_N = (N_NODES_C + 255) / 256;           // 391
  const int NB_E = N_EDGES_C / 256;                   // 12500 exact

  // ---- Tier A9: sorted-payload radix + fused MFMA aggregation (82.5 MB) ----
  const size_t A_SCT   = 0;                           // 400*784 ints
  const size_t A_COLP  = 1254400;
  const size_t A_BTOT  = 2508800;                     // 782 ints (pad)
  const size_t A_BOFF  = 2512000;                     // 783 ints (pad)
  const size_t A_BSUM  = 2515200;                     // 512 ints
  const size_t A_BIDS  = 2517248;                     // E ints (12.8 MB); agg aliases
  const size_t A_CL    = A_BIDS + 12800000;           // E ints (12.8 MB)
  const size_t A_EAB   = A_CL + 12800000;             // E uint4 (51.2 MB)
  const size_t A_XB    = A_EAB + 51200000;            // N*16 ushort (3.2 MB)
  const size_t A_NEED  = A_XB + 3200000;              // 82,517,248 B

  if (ws_size >= A_NEED) {
    int* sct   = (int*)(ws + A_SCT);
    int* colp  = (int*)(ws + A_COLP);
    int* btot  = (int*)(ws + A_BTOT);
    int* boff  = (int*)(ws + A_BOFF);
    int* bsum  = (int*)(ws + A_BSUM);
    int* bids  = (int*)(ws + A_BIDS);
    int* cl    = (int*)(ws + A_CL);
    uint4* eab = (uint4*)(ws + A_EAB);
    unsigned short* xb = (unsigned short*)(ws + A_XB);
    float* agg = (float*)(ws + A_BIDS);               // alias: bids dead after bscatter2

    hipLaunchKernelGGL(bucketize_kernel, dim3(NBLK_BUK), dim3(256), 0, stream,
                       edge_index, bids, sct);
    hipLaunchKernelGGL(colscan_kernel, dim3(NBUK), dim3(256), 0, stream,
                       sct, colp, btot);
    hipLaunchKernelGGL(scan_block, dim3((NBUK + 255) / 256), dim3(256), 0, stream,
                       btot, boff, bsum, NBUK);
    hipLaunchKernelGGL(scan_bsum, dim3(1), dim3(512), 0, stream,
                       bsum, (NBUK + 255) / 256);
    hipLaunchKernelGGL(scan_add, dim3((NBUK + 255) / 256), dim3(256), 0, stream,
                       boff, bsum, NBUK, N_EDGES_C);
    hipLaunchKernelGGL(bscatter2_kernel, dim3(NBLK_BUK), dim3(256), 0, stream,
                       bids, sct, colp, boff, edge_index, edge_attr, cl, eab);
    hipLaunchKernelGGL(xcast_kernel, dim3((N_NODES_C * 2 + 255) / 256), dim3(256),
                       0, stream, node_features, xb);
    hipLaunchKernelGGL(bagg5_kernel, dim3(NBUK), dim3(512), 0, stream,
                       boff, cl, eab, xb, W_msg_tp, W_msg_lin, agg);
    hipLaunchKernelGGL(node_kernel, dim3(NB_N), dim3(256), 0, stream,
                       node_features, agg, W_upd_tp, W_upd_lin, out);
  } else {
    float* agg = (float*)ws;
    const int n4 = N_NODES_C * 16 / 4;
    hipLaunchKernelGGL(zero_f4, dim3((n4 + 255) / 256), dim3(256), 0, stream,
                       (float4*)agg, n4);
    hipLaunchKernelGGL(edge_kernel, dim3(N_EDGES_C / (256 * EPT)), dim3(256), 0, stream,
                       node_features, edge_attr, W_msg_tp, W_msg_lin, edge_index, agg);
    hipLaunchKernelGGL(node_kernel, dim3(NB_N), dim3(256), 0, stream,
                       node_features, agg, W_upd_tp, W_upd_lin, out);
  }
}

// Round 20
// 443.998 us; speedup vs baseline: 1.2235x; 1.1120x over previous
//
#include <hip/hip_runtime.h>
#include <math.h>

#define N_NODES_C 100000
#define N_EDGES_C 3200000
// D_NODE=16, D_EDGE=8, D_HIDDEN=16

#define NORM_MSG_TP 0.08838834764831845f   // 1/sqrt(16*8)
#define NORM_UPD_TP 0.0625f                // 1/sqrt(16*16)
#define NORM_LIN    0.25f                  // 1/sqrt(16)

#define NBUK  782      // buckets of 128 nodes
#define NBUKP 784
#define BPB   8000     // edges per bucketize block: 3.2M/8000 = 400 exact
#define NBLK_BUK 400
#define SPLIT 4        // sub-blocks per bucket in bagg6

typedef float f32x4 __attribute__((ext_vector_type(4)));
typedef short bf16x8 __attribute__((ext_vector_type(8)));
typedef int   int4v  __attribute__((ext_vector_type(4)));

__device__ __forceinline__ float silu_f(float v) {
  return v / (1.0f + __expf(-v));
}

__device__ __forceinline__ void atomic_add_hw(float* p, float v) {
  unsafeAtomicAdd(p, v);
}

__device__ __forceinline__ unsigned int bf16_bits(float f) {
  unsigned int b = __float_as_uint(f);
  return (b + 0x7fffu + ((b >> 16) & 1u)) >> 16;
}
__device__ __forceinline__ unsigned int pack_bf16x2(float lo, float hi) {
  return bf16_bits(lo) | (bf16_bits(hi) << 16);
}
__device__ __forceinline__ float unlo(unsigned int w) { return __uint_as_float(w << 16); }
__device__ __forceinline__ float unhi(unsigned int w) { return __uint_as_float(w & 0xffff0000u); }

// ---------------- bucketize ----------------

__global__ __launch_bounds__(256) void bucketize_kernel(
    const int* __restrict__ row,
    int* __restrict__ bids, int* __restrict__ sct)
{
  __shared__ int lhist[NBUKP];
  __shared__ int lcur[NBUKP];
  __shared__ int partial[256];
  __shared__ int lids[BPB];
  const int t = threadIdx.x;
  const int base = blockIdx.x * BPB;

  for (int i = t; i < NBUKP; i += 256) lhist[i] = 0;
  __syncthreads();
  for (int k = t; k < BPB; k += 256)
    atomicAdd(&lhist[row[base + k] >> 7], 1);
  __syncthreads();

  int csum = 0;
  if (t < 196) {
    int s = 0;
#pragma unroll
    for (int j = 0; j < 4; ++j) {
      const int v = lhist[t * 4 + j];
      lhist[t * 4 + j] = s;
      s += v;
    }
    csum = s;
  }
  partial[t] = csum;
  __syncthreads();
  for (int o = 1; o < 256; o <<= 1) {
    int tv = (t >= o) ? partial[t - o] : 0;
    __syncthreads();
    partial[t] += tv;
    __syncthreads();
  }
  const int add = partial[t] - csum;
  if (t < 196) {
#pragma unroll
    for (int j = 0; j < 4; ++j) lhist[t * 4 + j] += add;
  }
  __syncthreads();
  for (int i = t; i < NBUKP; i += 256) lcur[i] = lhist[i];
  __syncthreads();

  for (int k = t; k < BPB; k += 256) {
    const int r = row[base + k];
    const int b = r >> 7;
    const int p = atomicAdd(&lcur[b], 1);
    lids[p] = ((base + k) << 7) | (r & 127);
  }
  __syncthreads();

  for (int i = t; i < NBUKP; i += 256)
    sct[blockIdx.x * NBUKP + i] = lhist[i];
  for (int k = t; k < BPB; k += 256)
    bids[base + k] = lids[k];
}

// ---------------- colscan ----------------

__global__ __launch_bounds__(256) void colscan_kernel(
    const int* __restrict__ sct, int* __restrict__ colpre, int* __restrict__ btot) {
  __shared__ int sa[512], sb[512];
  const int t = threadIdx.x;
  const int b = blockIdx.x;
  const int c0 = (t < NBLK_BUK)
      ? sct[t * NBUKP + b + 1] - sct[t * NBUKP + b] : 0;
  const int c1 = (t + 256 < NBLK_BUK)
      ? sct[(t + 256) * NBUKP + b + 1] - sct[(t + 256) * NBUKP + b] : 0;
  sa[t] = c0; sa[t + 256] = c1;
  int* src = sa; int* dst = sb;
  for (int o = 1; o < 512; o <<= 1) {
    __syncthreads();
    dst[t]       = src[t]       + ((t >= o) ? src[t - o] : 0);
    dst[t + 256] = src[t + 256] + ((t + 256 >= o) ? src[t + 256 - o] : 0);
    int* tmp = src; src = dst; dst = tmp;
  }
  __syncthreads();
  if (t < NBLK_BUK) colpre[t * NBUKP + b] = src[t] - c0;
  if (t + 256 < NBLK_BUK) colpre[(t + 256) * NBUKP + b] = src[t + 256] - c1;
  if (t == 0) btot[b] = src[NBLK_BUK - 1];
}

// ---------------- generic scans ----------------

__global__ __launch_bounds__(256) void scan_block(
    const int* __restrict__ cnt, int* __restrict__ off, int* __restrict__ bsum, int n) {
  __shared__ int s[256];
  const int t = threadIdx.x;
  const int i = blockIdx.x * 256 + t;
  const int v = (i < n) ? cnt[i] : 0;
  s[t] = v;
  __syncthreads();
#pragma unroll
  for (int o = 1; o < 256; o <<= 1) {
    int tv = (t >= o) ? s[t - o] : 0;
    __syncthreads();
    s[t] += tv;
    __syncthreads();
  }
  if (i < n) off[i] = s[t] - v;
  if (t == 255) bsum[blockIdx.x] = s[255];
}

__global__ void scan_bsum(int* __restrict__ bsum, int nb) {
  __shared__ int s[512];
  const int t = threadIdx.x;
  const int v = (t < nb) ? bsum[t] : 0;
  s[t] = v;
  __syncthreads();
#pragma unroll
  for (int o = 1; o < 512; o <<= 1) {
    int tv = (t >= o) ? s[t - o] : 0;
    __syncthreads();
    s[t] += tv;
    __syncthreads();
  }
  if (t < nb) bsum[t] = s[t] - v;
}

__global__ __launch_bounds__(256) void scan_add(
    int* __restrict__ off, const int* __restrict__ bsum, int n, int total) {
  int i = blockIdx.x * 256 + threadIdx.x;
  if (i < n) off[i] += bsum[blockIdx.x];
  if (i == 0) off[n] = total;
}

// ---------------- bscatter2 ----------------

__global__ __launch_bounds__(256) void bscatter2_kernel(
    const int* __restrict__ bids, const int* __restrict__ sct,
    const int* __restrict__ colpre, const int* __restrict__ boff,
    const int* __restrict__ eidx, const float* __restrict__ ea,
    int* __restrict__ cl, uint4* __restrict__ eab) {
  __shared__ int srow[NBUKP];
  __shared__ int crow[NBUKP];
  const int t = threadIdx.x;
  const int blk = blockIdx.x;
  for (int i = t; i < NBUKP; i += 256) {
    srow[i] = sct[blk * NBUKP + i];
    crow[i] = colpre[blk * NBUKP + i];
  }
  __syncthreads();
  for (int k = t; k < BPB; k += 256) {
    const int code = bids[blk * BPB + k];
    const int eid = code >> 7;
    const int local = code & 127;
    int lo = 0, hi = 783;
    while (hi - lo > 1) {
      const int mid = (lo + hi) >> 1;
      if (srow[mid] <= k) lo = mid; else hi = mid;
    }
    const int slot = boff[lo] + crow[lo] + (k - srow[lo]);
    const int col = eidx[N_EDGES_C + eid];
    cl[slot] = (local << 20) | col;
    const float4 a = *reinterpret_cast<const float4*>(ea + (size_t)eid * 8);
    const float4 b = *reinterpret_cast<const float4*>(ea + (size_t)eid * 8 + 4);
    uint4 w;
    w.x = pack_bf16x2(a.x, a.y);
    w.y = pack_bf16x2(a.z, a.w);
    w.z = pack_bf16x2(b.x, b.y);
    w.w = pack_bf16x2(b.z, b.w);
    eab[slot] = w;
  }
}

// ---------------- x -> bf16 table ----------------

__global__ __launch_bounds__(256) void xcast_kernel(
    const float* __restrict__ x, unsigned short* __restrict__ xb) {
  const int i = blockIdx.x * 256 + threadIdx.x;
  if (i < N_NODES_C * 2) {
    const float4 a = *reinterpret_cast<const float4*>(x + (size_t)i * 8);
    const float4 b = *reinterpret_cast<const float4*>(x + (size_t)i * 8 + 4);
    uint4 w;
    w.x = pack_bf16x2(a.x, a.y); w.y = pack_bf16x2(a.z, a.w);
    w.z = pack_bf16x2(b.x, b.y); w.w = pack_bf16x2(b.z, b.w);
    *reinterpret_cast<uint4*>(xb + (size_t)i * 8) = w;
  }
}

__global__ void zero_f4(float4* __restrict__ p, int n4) {
  int i = blockIdx.x * blockDim.x + threadIdx.x;
  if (i < n4) p[i] = make_float4(0.f, 0.f, 0.f, 0.f);
}

// ---------------- bagg6: flipped-orientation fused MFMA aggregation ----------------
// mfma(edge_frag, W_frag): C[row=edge=4g+reg][col=h=el] -> the 16 lanes of a
// group write 16 DIFFERENT h of an edge (conflict-free across lanes, <=4-way
// across groups). SPLIT sub-blocks per bucket for occupancy; private lagg
// merged into raw (pre-Wlin) global sums via HW fp32 atomics (L2-resident).

__global__ __launch_bounds__(512) void bagg6_kernel(
    const int* __restrict__ boff,     // [NBUK+1]
    const int* __restrict__ cl,       // [E] (local<<20)|col at sorted slot
    const uint4* __restrict__ eab,    // [E] bf16x8 ea at sorted slot
    const unsigned short* __restrict__ xb,  // [N,16] bf16
    const float* __restrict__ Wtp,    // [16,8,16]
    float* __restrict__ aggraw)       // [N,16] raw sums (zeroed)
{
  __shared__ float lagg[128][17];
  const int t = threadIdx.x;
  const int b   = blockIdx.x >> 2;    // bucket
  const int sub = blockIdx.x & 3;     // sub-block
  for (int i = t; i < 128 * 17; i += 512) (&lagg[0][0])[i] = 0.f;
  __syncthreads();

  const int lane  = t & 63;
  const int wv    = t >> 6;           // 8 waves
  const int el    = lane & 15;
  const int g     = lane >> 4;
  const int gsel  = g >> 1;
  const int ghalf = g & 1;

  // B frag (constant W): bq[q][tt] = Wtp[i=8*ghalf+tt][j=2q+gsel][h=el] (k=j*16+i)
  bf16x8 bq[4];
#pragma unroll
  for (int q = 0; q < 4; ++q) {
#pragma unroll
    for (int tt = 0; tt < 8; ++tt) {
      const float w = Wtp[(8 * ghalf + tt) * 128 + (2 * q + gsel) * 16 + el];
      bq[q][tt] = (short)bf16_bits(w);
    }
  }

  const int p0 = boff[b];
  const int p1 = boff[b + 1];

  // 32 virtual waves (8 waves x 4 sub-blocks), stride 512 slots
  for (int sbase = p0 + (sub * 8 + wv) * 16; sbase < p1; sbase += 32 * 16) {
    const int s = sbase + el;
    const bool ok = (s < p1);
    const int clv = ok ? cl[s] : 0;
    const int col = clv & 0xFFFFF;
    uint4 ev;
    if (ok) ev = eab[s];
    else { ev.x = ev.y = ev.z = ev.w = 0; }
    const uint4 xh = *reinterpret_cast<const uint4*>(
        xb + (size_t)col * 16 + 8 * ghalf);

    float xf[8];
    xf[0] = unlo(xh.x); xf[1] = unhi(xh.x);
    xf[2] = unlo(xh.y); xf[3] = unhi(xh.y);
    xf[4] = unlo(xh.z); xf[5] = unhi(xh.z);
    xf[6] = unlo(xh.w); xf[7] = unhi(xh.w);
    float eq[4];
    eq[0] = gsel ? unhi(ev.x) : unlo(ev.x);
    eq[1] = gsel ? unhi(ev.y) : unlo(ev.y);
    eq[2] = gsel ? unhi(ev.z) : unlo(ev.z);
    eq[3] = gsel ? unhi(ev.w) : unlo(ev.w);

    f32x4 acc = {0.f, 0.f, 0.f, 0.f};
#pragma unroll
    for (int q = 0; q < 4; ++q) {
      const float e_ = eq[q];
      const unsigned u0 = __float_as_uint(xf[0] * e_) + 0x8000u;
      const unsigned u1 = __float_as_uint(xf[1] * e_) + 0x8000u;
      const unsigned u2 = __float_as_uint(xf[2] * e_) + 0x8000u;
      const unsigned u3 = __float_as_uint(xf[3] * e_) + 0x8000u;
      const unsigned u4 = __float_as_uint(xf[4] * e_) + 0x8000u;
      const unsigned u5 = __float_as_uint(xf[5] * e_) + 0x8000u;
      const unsigned u6 = __float_as_uint(xf[6] * e_) + 0x8000u;
      const unsigned u7 = __float_as_uint(xf[7] * e_) + 0x8000u;
      int4v iv;
      iv.x = (int)__builtin_amdgcn_perm(u1, u0, 0x07060302u);
      iv.y = (int)__builtin_amdgcn_perm(u3, u2, 0x07060302u);
      iv.z = (int)__builtin_amdgcn_perm(u5, u4, 0x07060302u);
      iv.w = (int)__builtin_amdgcn_perm(u7, u6, 0x07060302u);
      union { int4v i; bf16x8 h; } cv; cv.i = iv;
      // flipped: A = edge fragment, B = W fragment
      acc = __builtin_amdgcn_mfma_f32_16x16x32_bf16(cv.h, bq[q], acc, 0, 0, 0);
    }

    // acc[reg] = m[edge = sbase+4g+reg][h = el]; locals via in-group shfl
#pragma unroll
    for (int reg = 0; reg < 4; ++reg) {
      const int ee = 4 * g + reg;
      if (sbase + ee < p1) {
        const int loc = __shfl(clv, ee, 16) >> 20;
        atomicAdd(&lagg[loc][el], silu_f(acc[reg] * NORM_MSG_TP));
      }
    }
  }
  __syncthreads();

  // merge raw sums into global (HW fp32 atomics, 6.4MB L2-resident region)
#pragma unroll
  for (int i = 0; i < 4; ++i) {
    const int idx = t * 4 + i;        // 0..2047
    const int node = idx >> 4, k2 = idx & 15;
    const int n = b * 128 + node;
    if (n < N_NODES_C) {
      const float v = lagg[node][k2];
      if (v != 0.f) atomic_add_hw(&aggraw[(size_t)n * 16 + k2], v);
    }
  }
}

// ---------------- node update (Wlin fused) ----------------

__global__ __launch_bounds__(256) void node_kernel2(
    const float* __restrict__ x, const float* __restrict__ aggraw,
    const float* __restrict__ Wmlin,  // [16,16] W_msg_lin
    const float* __restrict__ Wtp,    // [16,16,16] W_upd_tp
    const float* __restrict__ Wlin,   // [16,16]   W_upd_lin
    float* __restrict__ out)
{
  __shared__ float sW[4096];
  __shared__ float sM[256];
  __shared__ float sL[256];
  for (int t = threadIdx.x; t < 4096; t += 256) sW[t] = Wtp[t];
  sM[threadIdx.x] = Wmlin[threadIdx.x];
  sL[threadIdx.x] = Wlin[threadIdx.x];
  __syncthreads();

  const long n = (long)blockIdx.x * 256 + threadIdx.x;
  if (n >= N_NODES_C) return;

  float xr[16], araw[16], ar[16];
  const float4* xp = reinterpret_cast<const float4*>(x + (size_t)n * 16);
  const float4* ap = reinterpret_cast<const float4*>(aggraw + (size_t)n * 16);
#pragma unroll
  for (int q = 0; q < 4; ++q) {
    float4 v = xp[q];
    xr[q*4+0] = v.x; xr[q*4+1] = v.y; xr[q*4+2] = v.z; xr[q*4+3] = v.w;
    float4 w = ap[q];
    araw[q*4+0] = w.x; araw[q*4+1] = w.y; araw[q*4+2] = w.z; araw[q*4+3] = w.w;
  }
  // agg = NORM_LIN * araw @ Wmlin
#pragma unroll
  for (int h2 = 0; h2 < 16; ++h2) {
    float a = 0.f;
#pragma unroll
    for (int h = 0; h < 16; ++h) a = fmaf(araw[h], sM[h * 16 + h2], a);
    ar[h2] = a * NORM_LIN;
  }

  float u[16];
#pragma unroll
  for (int k = 0; k < 16; ++k) u[k] = 0.f;
#pragma unroll
  for (int i = 0; i < 16; ++i) {
#pragma unroll
    for (int h = 0; h < 16; ++h) {
      const float p = xr[i] * ar[h];
      const float* w = &sW[(i*16 + h) * 16];
#pragma unroll
      for (int k = 0; k < 16; ++k) u[k] = fmaf(p, w[k], u[k]);
    }
  }
  float g[16];
#pragma unroll
  for (int k = 0; k < 16; ++k) g[k] = silu_f(u[k] * NORM_UPD_TP);
  float res[16];
#pragma unroll
  for (int k2 = 0; k2 < 16; ++k2) {
    float a = 0.f;
#pragma unroll
    for (int k = 0; k < 16; ++k) a = fmaf(g[k], sL[k*16 + k2], a);
    res[k2] = xr[k2] + a * NORM_LIN;
  }
  float4* op = reinterpret_cast<float4*>(out + (size_t)n * 16);
#pragma unroll
  for (int q = 0; q < 4; ++q)
    op[q] = make_float4(res[q*4+0], res[q*4+1], res[q*4+2], res[q*4+3]);
}

// ---------------- Tier C fallback: atomic scatter ----------------

#define EPT 2
__global__ __launch_bounds__(256) void edge_kernel(
    const float* __restrict__ x, const float* __restrict__ ea,
    const float* __restrict__ Wtp, const float* __restrict__ Wlin,
    const int* __restrict__ eidx, float* __restrict__ agg)
{
  __shared__ float sW[2048];
  __shared__ float sL[256];
  for (int t = threadIdx.x; t < 2048; t += 256) sW[t] = Wtp[t];
  sL[threadIdx.x] = Wlin[threadIdx.x];
  __syncthreads();
  const long e0 = ((long)blockIdx.x * 256 + threadIdx.x) * EPT;
  float xr[EPT][16], er[EPT][8];
  int rw[EPT];
#pragma unroll
  for (int e = 0; e < EPT; ++e) {
    const long ei = e0 + e;
    const int c = eidx[N_EDGES_C + ei];
    rw[e] = eidx[ei];
    const float4* xp = reinterpret_cast<const float4*>(x + (size_t)c * 16);
#pragma unroll
    for (int q = 0; q < 4; ++q) {
      float4 v = xp[q];
      xr[e][q*4+0] = v.x; xr[e][q*4+1] = v.y; xr[e][q*4+2] = v.z; xr[e][q*4+3] = v.w;
    }
    const float4* ep = reinterpret_cast<const float4*>(ea + (size_t)ei * 8);
#pragma unroll
    for (int q = 0; q < 2; ++q) {
      float4 v = ep[q];
      er[e][q*4+0] = v.x; er[e][q*4+1] = v.y; er[e][q*4+2] = v.z; er[e][q*4+3] = v.w;
    }
  }
  float m[EPT][16];
#pragma unroll
  for (int e = 0; e < EPT; ++e)
#pragma unroll
    for (int h = 0; h < 16; ++h) m[e][h] = 0.f;
#pragma unroll
  for (int i = 0; i < 16; ++i) {
#pragma unroll
    for (int j = 0; j < 8; ++j) {
      float p[EPT];
#pragma unroll
      for (int e = 0; e < EPT; ++e) p[e] = xr[e][i] * er[e][j];
      const float* w = &sW[(i*8 + j) * 16];
#pragma unroll
      for (int h = 0; h < 16; ++h) {
        const float wv = w[h];
#pragma unroll
        for (int e = 0; e < EPT; ++e) m[e][h] = fmaf(p[e], wv, m[e][h]);
      }
    }
  }
#pragma unroll
  for (int e = 0; e < EPT; ++e) {
    float g[16];
#pragma unroll
    for (int h = 0; h < 16; ++h) g[h] = silu_f(m[e][h] * NORM_MSG_TP);
    float* ap = agg + (size_t)rw[e] * 16;
#pragma unroll
    for (int h2 = 0; h2 < 16; ++h2) {
      float a = 0.f;
#pragma unroll
      for (int h = 0; h < 16; ++h) a = fmaf(g[h], sL[h*16 + h2], a);
      atomic_add_hw(ap + h2, a * NORM_LIN);
    }
  }
}

__global__ __launch_bounds__(256) void node_kernel(
    const float* __restrict__ x, const float* __restrict__ agg,
    const float* __restrict__ Wtp, const float* __restrict__ Wlin,
    float* __restrict__ out)
{
  __shared__ float sW[4096];
  __shared__ float sL[256];
  for (int t = threadIdx.x; t < 4096; t += 256) sW[t] = Wtp[t];
  sL[threadIdx.x] = Wlin[threadIdx.x];
  __syncthreads();

  const long n = (long)blockIdx.x * 256 + threadIdx.x;
  if (n >= N_NODES_C) return;

  float xr[16], ar[16];
  const float4* xp = reinterpret_cast<const float4*>(x + (size_t)n * 16);
  const float4* ap = reinterpret_cast<const float4*>(agg + (size_t)n * 16);
#pragma unroll
  for (int q = 0; q < 4; ++q) {
    float4 v = xp[q];
    xr[q*4+0] = v.x; xr[q*4+1] = v.y; xr[q*4+2] = v.z; xr[q*4+3] = v.w;
    float4 w = ap[q];
    ar[q*4+0] = w.x; ar[q*4+1] = w.y; ar[q*4+2] = w.z; ar[q*4+3] = w.w;
  }
  float u[16];
#pragma unroll
  for (int k = 0; k < 16; ++k) u[k] = 0.f;
#pragma unroll
  for (int i = 0; i < 16; ++i) {
#pragma unroll
    for (int h = 0; h < 16; ++h) {
      const float p = xr[i] * ar[h];
      const float* w = &sW[(i*16 + h) * 16];
#pragma unroll
      for (int k = 0; k < 16; ++k) u[k] = fmaf(p, w[k], u[k]);
    }
  }
  float g[16];
#pragma unroll
  for (int k = 0; k < 16; ++k) g[k] = silu_f(u[k] * NORM_UPD_TP);
  float res[16];
#pragma unroll
  for (int k2 = 0; k2 < 16; ++k2) {
    float a = 0.f;
#pragma unroll
    for (int k = 0; k < 16; ++k) a = fmaf(g[k], sL[k*16 + k2], a);
    res[k2] = xr[k2] + a * NORM_LIN;
  }
  float4* op = reinterpret_cast<float4*>(out + (size_t)n * 16);
#pragma unroll
  for (int q = 0; q < 4; ++q)
    op[q] = make_float4(res[q*4+0], res[q*4+1], res[q*4+2], res[q*4+3]);
}

// ---------------- launch ----------------

extern "C" void kernel_launch(void* const* d_in, const int* in_sizes, int n_in,
                              void* d_out, int out_size, void* d_ws, size_t ws_size,
                              hipStream_t stream) {
  const float* node_features = (const float*)d_in[0];
  const float* edge_attr     = (const float*)d_in[1];
  const float* W_msg_tp      = (const float*)d_in[3];
  const float* W_msg_lin     = (const float*)d_in[4];
  const float* W_upd_tp      = (const float*)d_in[5];
  const float* W_upd_lin     = (const float*)d_in[6];
  const int*   edge_index    = (const int*)d_in[7];
  float* out = (float*)d_out;
  char* ws = (char*)d_ws;

  const int NB_N = (N_NODES_C + 255) / 256;           // 391
  const int NB_E = N_EDGES_C / 256;                   // 12500 exact

  // ---- Tier A10: sorted-payload radix + flipped fused MFMA agg (82.5 MB) ----
  const size_t A_SCT   = 0;
  const size_t A_COLP  = 1254400;
  const size_t A_BTOT  = 2508800;
  const size_t A_BOFF  = 2512000;
  const size_t A_BSUM  = 2515200;
  const size_t A_BIDS  = 2517248;                     // E ints; aggraw aliases
  const size_t A_CL    = A_BIDS + 12800000;           // E ints
  const size_t A_EAB   = A_CL + 12800000;             // E uint4
  const size_t A_XB    = A_EAB + 51200000;            // N*16 ushort
  const size_t A_NEED  = A_XB + 3200000;              // 82,517,248 B

  if (ws_size >= A_NEED) {
    int* sct   = (int*)(ws + A_SCT);
    int* colp  = (int*)(ws + A_COLP);
    int* btot  = (int*)(ws + A_BTOT);
    int* boff  = (int*)(ws + A_BOFF);
    int* bsum  = (int*)(ws + A_BSUM);
    int* bids  = (int*)(ws + A_BIDS);
    int* cl    = (int*)(ws + A_CL);
    uint4* eab = (uint4*)(ws + A_EAB);
    unsigned short* xb = (unsigned short*)(ws + A_XB);
    float* aggraw = (float*)(ws + A_BIDS);            // alias: bids dead after bscatter2

    hipLaunchKernelGGL(bucketize_kernel, dim3(NBLK_BUK), dim3(256), 0, stream,
                       edge_index, bids, sct);
    hipLaunchKernelGGL(colscan_kernel, dim3(NBUK), dim3(256), 0, stream,
                       sct, colp, btot);
    hipLaunchKernelGGL(scan_block, dim3((NBUK + 255) / 256), dim3(256), 0, stream,
                       btot, boff, bsum, NBUK);
    hipLaunchKernelGGL(scan_bsum, dim3(1), dim3(512), 0, stream,
                       bsum, (NBUK + 255) / 256);
    hipLaunchKernelGGL(scan_add, dim3((NBUK + 255) / 256), dim3(256), 0, stream,
                       boff, bsum, NBUK, N_EDGES_C);
    hipLaunchKernelGGL(bscatter2_kernel, dim3(NBLK_BUK), dim3(256), 0, stream,
                       bids, sct, colp, boff, edge_index, edge_attr, cl, eab);
    hipLaunchKernelGGL(xcast_kernel, dim3((N_NODES_C * 2 + 255) / 256), dim3(256),
                       0, stream, node_features, xb);
    // zero aggraw (aliases bids, safe: bids fully consumed by bscatter2)
    hipLaunchKernelGGL(zero_f4, dim3((N_NODES_C * 16 / 4 + 255) / 256), dim3(256),
                       0, stream, (float4*)aggraw, N_NODES_C * 16 / 4);
    hipLaunchKernelGGL(bagg6_kernel, dim3(NBUK * SPLIT), dim3(512), 0, stream,
                       boff, cl, eab, xb, W_msg_tp, aggraw);
    hipLaunchKernelGGL(node_kernel2, dim3(NB_N), dim3(256), 0, stream,
                       node_features, aggraw, W_msg_lin, W_upd_tp, W_upd_lin, out);
  } else {
    float* agg = (float*)ws;
    const int n4 = N_NODES_C * 16 / 4;
    hipLaunchKernelGGL(zero_f4, dim3((n4 + 255) / 256), dim3(256), 0, stream,
                       (float4*)agg, n4);
    hipLaunchKernelGGL(edge_kernel, dim3(N_EDGES_C / (256 * EPT)), dim3(256), 0, stream,
                       node_features, edge_attr, W_msg_tp, W_msg_lin, edge_index, agg);
    hipLaunchKernelGGL(node_kernel, dim3(NB_N), dim3(256), 0, stream,
                       node_features, agg, W_upd_tp, W_upd_lin, out);
  }
}